// Round 4
// baseline (6915.450 us; speedup 1.0000x reference)
//
#include <hip/hip_runtime.h>
#include <math.h>

#define BB 64
#define SS 512
#define DD 207
#define HH 256
#define NWG 64
#define GB 32     // batch-group width (two groups of 32)
#define LDW 676   // wgl row stride (%32==4 -> staggered banks)
#define ROW 260   // wrol row stride
#define AG __HIP_MEMORY_SCOPE_AGENT

// ================= v10: two batch groups, phase-shifted pipeline =============
// 64 WGs x 512 threads (8 waves, 2/SIMD — the proven v7 occupancy).
// Batches 0-31 = group A, 32-63 = group B: independent recurrences,
// phase-shifted so each barrier's cross-XCD propagation is hidden behind the
// other group's GEMV compute. Slot rotation now per (t, group):
//   slot(t,g) rows 0..413: xin, 414/415 pad, 416..671: h   (32 floats/row)
// Same publish protocol as v6/v7: writers sc1 (ast4), readers NORMAL loads of
// virgin addresses, flag-gated; flags sc1, monotone. Per group per step:
// arr1 (xin ready), arr2 (h ready). 4 barriers/step, all compute-covered.
// GEMV phases keep v7 FMA density at half batch width via 2 k-substreams/wave
// (lane bit 3): per 8k block, substream ks handles cols k+4*ks..k+4*ks+3.
#define SROWS 672
#define HOFF  416
#define BUF_FLOATS ((size_t)SS * 2 * SROWS * GB)   // == old 512*672*64
#define FLAG_U32 (64 * 32)
#define STAGE_FLOATS ((size_t)SS * DD * 64)
#define WS_NEED6 ((BUF_FLOATS + FLAG_U32 + STAGE_FLOATS) * sizeof(float))

// ---- v3 fallback layout (round-3 proven path) ----
#define V3_AROWS 928
#define V3_HBASE 416
#define V3_ACT (V3_AROWS * 64)
#define V3_FLAGS (64 * 32)
#define V3_WS_SMALL ((size_t)(V3_ACT + V3_FLAGS) * sizeof(float))
#define V3_WS_FULL  ((size_t)(V3_ACT + V3_FLAGS + STAGE_FLOATS) * sizeof(float))

__device__ __forceinline__ void ast4(float* p, float v) {
    union { float f; unsigned u; } c; c.f = v;
    __hip_atomic_store((unsigned*)p, c.u, __ATOMIC_RELAXED, AG);
}

// ---- 12-row gate GEMV partial, 32-batch, 2 k-substreams per wave ----
// lane = u(2b) | ks(1b) | bp(3b): u = rows {u,4+u,8+u}, ks = k-substream,
// bp = batch float4. Writes half-slot (slot*2+ks) of red (8 float4 per row).
__device__ __forceinline__ void run_range32(
    const float4* __restrict__ A4, const float* __restrict__ wgl,
    float* __restrict__ red, int u, int ks, int bp,
    int wc0, size_t gr0, int len, int slot)
{
    float4 c0 = make_float4(0.f, 0.f, 0.f, 0.f);
    float4 c1 = c0, c2 = c0;
    const int ko = ks * 4;
    #pragma unroll 4
    for (int k = 0; k < len; k += 8) {
        size_t r = (gr0 + k + ko) * 8 + bp;
        float4 a0 = A4[r + 0 * 8];
        float4 a1 = A4[r + 1 * 8];
        float4 a2 = A4[r + 2 * 8];
        float4 a3 = A4[r + 3 * 8];
        const int wc = wc0 + k + ko;
        float4 w0 = *(const float4*)&wgl[(0 + u) * LDW + wc];
        float4 w1 = *(const float4*)&wgl[(4 + u) * LDW + wc];
        float4 w2 = *(const float4*)&wgl[(8 + u) * LDW + wc];
        c0.x += a0.x*w0.x + a1.x*w0.y + a2.x*w0.z + a3.x*w0.w;
        c0.y += a0.y*w0.x + a1.y*w0.y + a2.y*w0.z + a3.y*w0.w;
        c0.z += a0.z*w0.x + a1.z*w0.y + a2.z*w0.z + a3.z*w0.w;
        c0.w += a0.w*w0.x + a1.w*w0.y + a2.w*w0.z + a3.w*w0.w;
        c1.x += a0.x*w1.x + a1.x*w1.y + a2.x*w1.z + a3.x*w1.w;
        c1.y += a0.y*w1.x + a1.y*w1.y + a2.y*w1.z + a3.y*w1.w;
        c1.z += a0.z*w1.x + a1.z*w1.y + a2.z*w1.z + a3.z*w1.w;
        c1.w += a0.w*w1.x + a1.w*w1.y + a2.w*w1.z + a3.w*w1.w;
        c2.x += a0.x*w2.x + a1.x*w2.y + a2.x*w2.z + a3.x*w2.w;
        c2.y += a0.y*w2.x + a1.y*w2.y + a2.y*w2.z + a3.y*w2.w;
        c2.z += a0.z*w2.x + a1.z*w2.y + a2.z*w2.z + a3.z*w2.w;
        c2.w += a0.w*w2.x + a1.w*w2.y + a2.w*w2.z + a3.w*w2.w;
    }
    float4* R4 = (float4*)red;
    const int hs = slot * 2 + ks;
    R4[(hs * 12 + 0 + u) * 8 + bp] = c0;
    R4[(hs * 12 + 4 + u) * 8 + bp] = c1;
    R4[(hs * 12 + 8 + u) * 8 + bp] = c2;
}

// ---- readout partials, 32-batch: wave wv covers 32 cols, 2 substreams of 16 ----
__device__ __forceinline__ void phaseB32(
    const float* __restrict__ hrow, const float* __restrict__ wrol,
    float* __restrict__ redB, int wv, int pks, int pb)
{
    const int jb = wv * 32 + pks * 16;
    float acc0 = 0.f, acc1 = 0.f, acc2 = 0.f, acc3 = 0.f;
    #pragma unroll
    for (int j = 0; j < 16; j += 4) {
        float a0 = hrow[(jb + j + 0) * GB + pb];
        float a1 = hrow[(jb + j + 1) * GB + pb];
        float a2 = hrow[(jb + j + 2) * GB + pb];
        float a3 = hrow[(jb + j + 3) * GB + pb];
        float4 w0 = *(const float4*)&wrol[0 * ROW + jb + j];
        float4 w1 = *(const float4*)&wrol[1 * ROW + jb + j];
        float4 w2 = *(const float4*)&wrol[2 * ROW + jb + j];
        float4 w3 = *(const float4*)&wrol[3 * ROW + jb + j];
        acc0 += a0*w0.x + a1*w0.y + a2*w0.z + a3*w0.w;
        acc1 += a0*w1.x + a1*w1.y + a2*w1.z + a3*w1.w;
        acc2 += a0*w2.x + a1*w2.y + a2*w2.z + a3*w2.w;
        acc3 += a0*w3.x + a1*w3.y + a2*w3.z + a3*w3.w;
    }
    const int hs = wv * 2 + pks;
    redB[(hs * 4 + 0) * GB + pb] = acc0;
    redB[(hs * 4 + 1) * GB + pb] = acc1;
    redB[(hs * 4 + 2) * GB + pb] = acc2;
    redB[(hs * 4 + 3) * GB + pb] = acc3;
}

__global__ __launch_bounds__(256) void rnn_init10(float* __restrict__ ws) {
    int i = blockIdx.x * blockDim.x + threadIdx.x;
    // zero h rows of slot (t=0, g) for g=0,1
    for (int idx = i; idx < 2 * HH * GB; idx += gridDim.x * blockDim.x) {
        int g = idx / (HH * GB);
        int j = idx - g * (HH * GB);
        ws[((size_t)(g * SROWS) + HOFF) * GB + j] = 0.f;
    }
    unsigned* fl = (unsigned*)(ws + BUF_FLOATS);
    for (int idx = i; idx < FLAG_U32; idx += gridDim.x * blockDim.x)
        fl[idx] = 0u;
}

__global__ __launch_bounds__(512) void rnn_persist10(
    const float* __restrict__ x, const float* __restrict__ mask,
    const float* __restrict__ W_ih, const float* __restrict__ W_hh,
    const float* __restrict__ b_ih, const float* __restrict__ b_hh,
    const float* __restrict__ W_ro, const float* __restrict__ b_ro,
    float* __restrict__ ws, float* __restrict__ out)
{
    const int wg = blockIdx.x;
    const int tid = threadIdx.x;
    const int lane = tid & 63;
    const int wv = tid >> 6;            // 0..7

    float* buf = ws;
    unsigned* flags = (unsigned*)(ws + BUF_FLOATS);
    float* stage = ws + BUF_FLOATS + FLAG_U32;

    __shared__ float wgl[12 * LDW];       // 12 gate rows x 676 (414/415 = 0)
    __shared__ float wrol[4 * ROW];       // up to 4 readout rows
    __shared__ float red[32 * 12 * GB];   // 32 half-slots: 0-15 xin, 16-31 gh
    __shared__ float redB[16 * 4 * GB];   // readout partials (16 half-slots)
    __shared__ float hloc[2 * 128];       // own hidden units per group
    __shared__ float bihl[12], bhhl[12], brol[4];

    const int d0 = (207 * wg) / NWG;
    const int d1 = (207 * (wg + 1)) / NWG;
    const int dc = d1 - d0;

    for (int i = tid; i < 12 * LDW; i += 512) {
        int r = i / LDW, c = i - r * LDW;
        int rg = (r >> 2) * 256 + wg * 4 + (r & 3);
        float v = 0.f;
        if (c < 414) v = W_ih[rg * 414 + c];
        else if (c >= 416 && c < 672) v = W_hh[rg * 256 + (c - 416)];
        wgl[i] = v;
    }
    for (int i = tid; i < 4 * 256; i += 512) {
        int dl_ = i >> 8, j = i & 255;
        wrol[dl_ * ROW + j] = (dl_ < dc) ? W_ro[(d0 + dl_) * 256 + j] : 0.f;
    }
    if (tid < 12) {
        int rg = (tid >> 2) * 256 + wg * 4 + (tid & 3);
        bihl[tid] = b_ih[rg];
        bhhl[tid] = b_hh[rg];
    }
    if (tid < 4) brol[tid] = (tid < dc) ? b_ro[d0 + tid] : 0.f;
    if (tid < 256) hloc[tid] = 0.f;
    __syncthreads();

    const float4* A4 = (const float4*)buf;
    const int u  = lane >> 4;           // 0..3 (gate-unit group)
    const int ks = (lane >> 3) & 1;     // k-substream
    const int bp = lane & 7;            // batch float4
    const int pb_b  = lane & 31;        // Phase B: batch element
    const int pb_ks = lane >> 5;        // Phase B: k-substream

    const bool have = (tid < dc * 32);
    const int dl = tid >> 5, bb = tid & 31;
    const size_t gbaseA = (size_t)bb * (SS * DD) + (d0 + dl);
    const size_t gbaseB = (size_t)(32 + bb) * (SS * DD) + (d0 + dl);
    float xvA = 0.f, mvA = 0.f, xvB = 0.f, mvB = 0.f;
    if (have) {
        xvA = x[gbaseA]; mvA = mask[gbaseA];
        xvB = x[gbaseB]; mvB = mask[gbaseB];
    }

    // xin row split: waves 0-5 -> 56 rows, waves 6-7 -> 40 rows (416 total)
    const int xr0  = (wv < 6) ? wv * 56 : 336 + (wv - 6) * 40;
    const int xlen = (wv < 6) ? 56 : 40;

    unsigned genA = 0, genB = 0;

    for (int t = 0; t < SS; ++t) {
        const size_t srowA = (size_t)(t * 2 + 0) * SROWS;
        const size_t srowB = (size_t)(t * 2 + 1) * SROWS;

        // ---- Phase B (A): readout partials from h_A[t] ----
        phaseB32(buf + (srowA + HOFF) * GB, wrol, redB, wv, pb_ks, pb_b);
        __syncthreads();
        if (have) {
            float xh = brol[dl];
            #pragma unroll
            for (int s = 0; s < 16; ++s) xh += redB[(s * 4 + dl) * GB + bb];
            stage[(t * DD + d0 + dl) * 64 + bb] = xh;
            if (t < SS - 1) {
                float xi = (mvA > 0.5f) ? xvA : xh;
                ast4(&buf[(srowA + d0 + dl) * GB + bb], xi);
                ast4(&buf[(srowA + 207 + d0 + dl) * GB + bb], mvA);
            }
        }
        if (t == SS - 1) {
            // finish group B's last readout (h_B[t] published at iter t-1)
            if (tid < 64) {
                unsigned* f = &flags[tid * 32 + 8];
                while (__hip_atomic_load(f, __ATOMIC_RELAXED, AG) < genB) {}
            }
            __syncthreads();
            phaseB32(buf + (srowB + HOFF) * GB, wrol, redB, wv, pb_ks, pb_b);
            __syncthreads();
            if (have) {
                float xh = brol[dl];
                #pragma unroll
                for (int s = 0; s < 16; ++s) xh += redB[(s * 4 + dl) * GB + bb];
                stage[(t * DD + d0 + dl) * 64 + 32 + bb] = xh;
            }
            break;
        }

        // ---- arrive 1A: xin_A published ----
        ++genA;
        asm volatile("s_waitcnt vmcnt(0)" ::: "memory");
        __syncthreads();
        if (tid == 0)
            __hip_atomic_store(&flags[wg * 32 + 0], genA, __ATOMIC_RELAXED, AG);

        // ---- wait 2B: h_B[t] ready (covered by prev-iter tail + Phase B A) ----
        if (tid < 64) {
            unsigned* f = &flags[tid * 32 + 8];
            while (__hip_atomic_load(f, __ATOMIC_RELAXED, AG) < genB) {}
        }
        __syncthreads();

        // ---- Phase B (B) ----
        phaseB32(buf + (srowB + HOFF) * GB, wrol, redB, wv, pb_ks, pb_b);
        __syncthreads();
        if (have) {
            float xh = brol[dl];
            #pragma unroll
            for (int s = 0; s < 16; ++s) xh += redB[(s * 4 + dl) * GB + bb];
            stage[(t * DD + d0 + dl) * 64 + 32 + bb] = xh;
            float xi = (mvB > 0.5f) ? xvB : xh;
            ast4(&buf[(srowB + d0 + dl) * GB + bb], xi);
            ast4(&buf[(srowB + 207 + d0 + dl) * GB + bb], mvB);
        }

        // ---- arrive 1B ----
        ++genB;
        asm volatile("s_waitcnt vmcnt(0)" ::: "memory");
        __syncthreads();
        if (tid == 0)
            __hip_atomic_store(&flags[wg * 32 + 8], genB, __ATOMIC_RELAXED, AG);

        // ---- gh_A (h_A rows L1/L2-hot from Phase B A); covers arr1B prop ----
        run_range32(A4, wgl, red, u, ks, bp, 416 + wv * 32,
                    srowA + HOFF + wv * 32, 32, 8 + wv);

        // ---- wait 1A (covered by PhaseB_B + gh_A since arr1A) ----
        if (tid < 64) {
            unsigned* f = &flags[tid * 32 + 0];
            while (__hip_atomic_load(f, __ATOMIC_RELAXED, AG) < genA) {}
        }
        __syncthreads();

        // ---- xin GEMV A (virgin cached reads) ----
        run_range32(A4, wgl, red, u, ks, bp, xr0, srowA + xr0, xlen, wv);
        __syncthreads();

        // ---- combine A + publish h_A[t+1] ----
        if (tid < 128) {
            const int u2 = tid >> 5, b2 = tid & 31;
            float gir = bihl[0 + u2], giz = bihl[4 + u2], gin = bihl[8 + u2];
            float ghr = bhhl[0 + u2], ghz = bhhl[4 + u2], ghn = bhhl[8 + u2];
            #pragma unroll
            for (int s = 0; s < 16; ++s) {
                gir += red[(s * 12 + 0 + u2) * GB + b2];
                giz += red[(s * 12 + 4 + u2) * GB + b2];
                gin += red[(s * 12 + 8 + u2) * GB + b2];
                ghr += red[((16 + s) * 12 + 0 + u2) * GB + b2];
                ghz += red[((16 + s) * 12 + 4 + u2) * GB + b2];
                ghn += red[((16 + s) * 12 + 8 + u2) * GB + b2];
            }
            float r = 1.f / (1.f + __expf(-(gir + ghr)));
            float z = 1.f / (1.f + __expf(-(giz + ghz)));
            float n = tanhf(gin + r * ghn);
            float hn = (1.f - z) * n + z * hloc[u2 * 32 + b2];
            hloc[u2 * 32 + b2] = hn;
            ast4(&buf[((size_t)((t + 1) * 2 + 0) * SROWS + HOFF + wg * 4 + u2) * GB + b2], hn);
        }

        // ---- arrive 2A ----
        ++genA;
        asm volatile("s_waitcnt vmcnt(0)" ::: "memory");
        __syncthreads();
        if (tid == 0)
            __hip_atomic_store(&flags[wg * 32 + 0], genA, __ATOMIC_RELAXED, AG);

        // ---- gh_B; covers arr2A prop ----
        run_range32(A4, wgl, red, u, ks, bp, 416 + wv * 32,
                    srowB + HOFF + wv * 32, 32, 8 + wv);

        // ---- wait 1B (covered by gh_A..combine_A + gh_B since arr1B) ----
        if (tid < 64) {
            unsigned* f = &flags[tid * 32 + 8];
            while (__hip_atomic_load(f, __ATOMIC_RELAXED, AG) < genB) {}
        }
        __syncthreads();

        // ---- xin GEMV B ----
        run_range32(A4, wgl, red, u, ks, bp, xr0, srowB + xr0, xlen, wv);
        __syncthreads();

        // ---- combine B + publish h_B[t+1] ----
        if (tid < 128) {
            const int u2 = tid >> 5, b2 = tid & 31;
            float gir = bihl[0 + u2], giz = bihl[4 + u2], gin = bihl[8 + u2];
            float ghr = bhhl[0 + u2], ghz = bhhl[4 + u2], ghn = bhhl[8 + u2];
            #pragma unroll
            for (int s = 0; s < 16; ++s) {
                gir += red[(s * 12 + 0 + u2) * GB + b2];
                giz += red[(s * 12 + 4 + u2) * GB + b2];
                gin += red[(s * 12 + 8 + u2) * GB + b2];
                ghr += red[((16 + s) * 12 + 0 + u2) * GB + b2];
                ghz += red[((16 + s) * 12 + 4 + u2) * GB + b2];
                ghn += red[((16 + s) * 12 + 8 + u2) * GB + b2];
            }
            float r = 1.f / (1.f + __expf(-(gir + ghr)));
            float z = 1.f / (1.f + __expf(-(giz + ghz)));
            float n = tanhf(gin + r * ghn);
            float hn = (1.f - z) * n + z * hloc[128 + u2 * 32 + b2];
            hloc[128 + u2 * 32 + b2] = hn;
            ast4(&buf[((size_t)((t + 1) * 2 + 1) * SROWS + HOFF + wg * 4 + u2) * GB + b2], hn);
        }

        // ---- arrive 2B ----
        ++genB;
        asm volatile("s_waitcnt vmcnt(0)" ::: "memory");
        __syncthreads();
        if (tid == 0)
            __hip_atomic_store(&flags[wg * 32 + 8], genB, __ATOMIC_RELAXED, AG);

        // ---- prefetch next x/mask (both groups); covers arr2B prop ----
        if (have && t + 1 < SS - 1) {
            xvA = x[gbaseA + (size_t)(t + 1) * DD];
            mvA = mask[gbaseA + (size_t)(t + 1) * DD];
            xvB = x[gbaseB + (size_t)(t + 1) * DD];
            mvB = mask[gbaseB + (size_t)(t + 1) * DD];
        }

        // ---- wait 2A (covered by gh_B..combine_B + prefetch since arr2A) ----
        if (tid < 64) {
            unsigned* f = &flags[tid * 32 + 0];
            while (__hip_atomic_load(f, __ATOMIC_RELAXED, AG) < genA) {}
        }
        __syncthreads();
    }
}

// epilogue: stage[t][d][b] -> out[b][t][d]
__global__ __launch_bounds__(256) void out_transpose(
    const float* __restrict__ stage, float* __restrict__ out)
{
    __shared__ float lds[DD * 65];
    const int t = blockIdx.x;
    const float* st = stage + (size_t)t * DD * 64;
    for (int i = threadIdx.x; i < DD * 64; i += 256) {
        int d = i >> 6, b = i & 63;
        lds[d * 65 + b] = st[i];
    }
    __syncthreads();
    for (int i = threadIdx.x; i < DD * 64; i += 256) {
        int b = i / DD, d = i - b * DD;
        out[(size_t)b * (SS * DD) + (size_t)t * DD + d] = lds[d * 65 + b];
    }
}

// ================= v3 middle fallback (round-3 proven, 8.1 ms) =================
__device__ __forceinline__ void run_range6(
    const float4* __restrict__ A4, const float* __restrict__ wgl,
    float* __restrict__ red, int u, int bp, int wc0, int gr0, int len, int slot)
{
    float4 c0 = make_float4(0.f, 0.f, 0.f, 0.f);
    float4 c1 = c0, c2 = c0;
    #pragma unroll 4
    for (int k = 0; k < len; k += 4) {
        float4 a0 = A4[(gr0 + k + 0) * 16 + bp];
        float4 a1 = A4[(gr0 + k + 1) * 16 + bp];
        float4 a2 = A4[(gr0 + k + 2) * 16 + bp];
        float4 a3 = A4[(gr0 + k + 3) * 16 + bp];
        float4 w0 = *(const float4*)&wgl[(0 + u) * LDW + wc0 + k];
        float4 w1 = *(const float4*)&wgl[(4 + u) * LDW + wc0 + k];
        float4 w2 = *(const float4*)&wgl[(8 + u) * LDW + wc0 + k];
        c0.x += a0.x*w0.x + a1.x*w0.y + a2.x*w0.z + a3.x*w0.w;
        c0.y += a0.y*w0.x + a1.y*w0.y + a2.y*w0.z + a3.y*w0.w;
        c0.z += a0.z*w0.x + a1.z*w0.y + a2.z*w0.z + a3.z*w0.w;
        c0.w += a0.w*w0.x + a1.w*w0.y + a2.w*w0.z + a3.w*w0.w;
        c1.x += a0.x*w1.x + a1.x*w1.y + a2.x*w1.z + a3.x*w1.w;
        c1.y += a0.y*w1.x + a1.y*w1.y + a2.y*w1.z + a3.y*w1.w;
        c1.z += a0.z*w1.x + a1.z*w1.y + a2.z*w1.z + a3.z*w1.w;
        c1.w += a0.w*w1.x + a1.w*w1.y + a2.w*w1.z + a3.w*w1.w;
        c2.x += a0.x*w2.x + a1.x*w2.y + a2.x*w2.z + a3.x*w2.w;
        c2.y += a0.y*w2.x + a1.y*w2.y + a2.y*w2.z + a3.y*w2.w;
        c2.z += a0.z*w2.x + a1.z*w2.y + a2.z*w2.z + a3.z*w2.w;
        c2.w += a0.w*w2.x + a1.w*w2.y + a2.w*w2.z + a3.w*w2.w;
    }
    float4* R4 = (float4*)red;
    R4[(slot * 12 + 0 + u) * 16 + bp] = c0;
    R4[(slot * 12 + 4 + u) * 16 + bp] = c1;
    R4[(slot * 12 + 8 + u) * 16 + bp] = c2;
}

__device__ __forceinline__ void v3_gbar(unsigned* flags, int wg, unsigned g) {
    __syncthreads();
    if (threadIdx.x < 64) {
        if (threadIdx.x == 0) {
            __builtin_amdgcn_fence(__ATOMIC_RELEASE, "agent");
            __hip_atomic_store(&flags[wg * 32], g, __ATOMIC_RELAXED, AG);
        }
        unsigned* f = &flags[threadIdx.x * 32];
        while (__hip_atomic_load(f, __ATOMIC_RELAXED, AG) < g) { }
        __builtin_amdgcn_fence(__ATOMIC_ACQUIRE, "agent");
    }
    __syncthreads();
}

__global__ __launch_bounds__(256) void v3_init(float* __restrict__ ws) {
    int i = blockIdx.x * blockDim.x + threadIdx.x;
    const int nz = (672 - 414) * 64;
    for (int idx = i; idx < nz; idx += gridDim.x * blockDim.x)
        ws[414 * 64 + idx] = 0.f;
    for (int idx = i; idx < V3_FLAGS; idx += gridDim.x * blockDim.x)
        ((unsigned*)(ws + V3_ACT))[idx] = 0u;
}

template<bool STAGE>
__global__ __launch_bounds__(256) void v3_persist(
    const float* __restrict__ x, const float* __restrict__ mask,
    const float* __restrict__ W_ih, const float* __restrict__ W_hh,
    const float* __restrict__ b_ih, const float* __restrict__ b_hh,
    const float* __restrict__ W_ro, const float* __restrict__ b_ro,
    float* __restrict__ ws, float* __restrict__ out)
{
    const int wg = blockIdx.x;
    const int tid = threadIdx.x;
    const int lane = tid & 63;
    const int wv = tid >> 6;

    float* actg = ws;
    unsigned* flags = (unsigned*)(ws + V3_ACT);
    float* stage = ws + V3_ACT + V3_FLAGS;

    __shared__ float wgl[12 * LDW];
    __shared__ float wrol[4 * 256];
    __shared__ float red[5 * 12 * 64];
    __shared__ float redB[16 * 64];
    __shared__ float hloc[4 * 64];
    __shared__ float bihl[12], bhhl[12], brol[4];

    const int d0 = (207 * wg) / NWG;
    const int d1 = (207 * (wg + 1)) / NWG;
    const int dc = d1 - d0;

    for (int i = tid; i < 12 * LDW; i += 256) {
        int r = i / LDW, c = i - r * LDW;
        int rg = (r >> 2) * 256 + wg * 4 + (r & 3);
        float v = 0.f;
        if (c < 414) v = W_ih[rg * 414 + c];
        else if (c >= 416 && c < 672) v = W_hh[rg * 256 + (c - 416)];
        wgl[i] = v;
    }
    for (int i = tid; i < 4 * 256; i += 256) {
        int dl_ = i >> 8, j = i & 255;
        wrol[i] = (dl_ < dc) ? W_ro[(d0 + dl_) * 256 + j] : 0.f;
    }
    if (tid < 12) {
        int rg = (tid >> 2) * 256 + wg * 4 + (tid & 3);
        bihl[tid] = b_ih[rg];
        bhhl[tid] = b_hh[rg];
    }
    if (tid < 4) brol[tid] = (tid < dc) ? b_ro[d0 + tid] : 0.f;
    hloc[tid] = 0.f;
    __syncthreads();

    const float4* A4 = (const float4*)actg;
    const int u = lane >> 4;
    const int bp = lane & 15;

    const bool have = (tid < dc * 64);
    const int dl = tid >> 6, b = tid & 63;
    const size_t gbase = (size_t)b * (SS * DD) + (d0 + dl);
    float xv_pf = 0.f, mv_pf = 0.f;
    if (have) { xv_pf = x[gbase]; mv_pf = mask[gbase]; }

    unsigned gen = 0;

    for (int t = 0; t < SS; ++t) {
        const int par = t & 1;
        const int hrow0 = V3_HBASE + par * 256;

        {
            const float* hrow = actg + hrow0 * 64;
            const int jb = wv * 64;
            float acc0 = 0.f, acc1 = 0.f, acc2 = 0.f, acc3 = 0.f;
            #pragma unroll 4
            for (int j = 0; j < 64; j += 4) {
                float a0 = hrow[(jb + j + 0) * 64 + lane];
                float a1 = hrow[(jb + j + 1) * 64 + lane];
                float a2 = hrow[(jb + j + 2) * 64 + lane];
                float a3 = hrow[(jb + j + 3) * 64 + lane];
                float4 w0 = *(const float4*)&wrol[0 * 256 + jb + j];
                float4 w1 = *(const float4*)&wrol[1 * 256 + jb + j];
                float4 w2 = *(const float4*)&wrol[2 * 256 + jb + j];
                float4 w3 = *(const float4*)&wrol[3 * 256 + jb + j];
                acc0 += a0*w0.x + a1*w0.y + a2*w0.z + a3*w0.w;
                acc1 += a0*w1.x + a1*w1.y + a2*w1.z + a3*w1.w;
                acc2 += a0*w2.x + a1*w2.y + a2*w2.z + a3*w2.w;
                acc3 += a0*w3.x + a1*w3.y + a2*w3.z + a3*w3.w;
            }
            redB[(wv * 4 + 0) * 64 + lane] = acc0;
            redB[(wv * 4 + 1) * 64 + lane] = acc1;
            redB[(wv * 4 + 2) * 64 + lane] = acc2;
            redB[(wv * 4 + 3) * 64 + lane] = acc3;
        }
        __syncthreads();
        if (have) {
            float xh = redB[(0 * 4 + dl) * 64 + b] + redB[(1 * 4 + dl) * 64 + b]
                     + redB[(2 * 4 + dl) * 64 + b] + redB[(3 * 4 + dl) * 64 + b]
                     + brol[dl];
            if (STAGE) stage[(t * DD + d0 + dl) * 64 + b] = xh;
            else       out[gbase + (size_t)t * DD] = xh;
            if (t < SS - 1) {
                float xi = (mv_pf > 0.5f) ? xv_pf : xh;
                actg[(d0 + dl) * 64 + b] = xi;
                actg[(207 + d0 + dl) * 64 + b] = mv_pf;
            }
        }
        if (t == SS - 1) break;

        if (have && t + 1 < SS - 1) {
            xv_pf = x[gbase + (size_t)(t + 1) * DD];
            mv_pf = mask[gbase + (size_t)(t + 1) * DD];
        }

        v3_gbar(flags, wg, ++gen);

        if (wv == 0)      run_range6(A4, wgl, red, u, bp, 0,   0,          168, 0);
        else if (wv == 1) run_range6(A4, wgl, red, u, bp, 168, 168,        168, 1);
        else if (wv == 2) {
            run_range6(A4, wgl, red, u, bp, 336, 336,        80,  2);
            run_range6(A4, wgl, red, u, bp, 416, hrow0,      96,  3);
        } else            run_range6(A4, wgl, red, u, bp, 512, hrow0 + 96, 160, 4);
        __syncthreads();
        {
            const int u2 = tid >> 6, b2 = tid & 63;
            float gir = red[(0*12 + 0 + u2)*64 + b2] + red[(1*12 + 0 + u2)*64 + b2]
                      + red[(2*12 + 0 + u2)*64 + b2] + bihl[0 + u2];
            float giz = red[(0*12 + 4 + u2)*64 + b2] + red[(1*12 + 4 + u2)*64 + b2]
                      + red[(2*12 + 4 + u2)*64 + b2] + bihl[4 + u2];
            float gin = red[(0*12 + 8 + u2)*64 + b2] + red[(1*12 + 8 + u2)*64 + b2]
                      + red[(2*12 + 8 + u2)*64 + b2] + bihl[8 + u2];
            float ghr = red[(3*12 + 0 + u2)*64 + b2] + red[(4*12 + 0 + u2)*64 + b2] + bhhl[0 + u2];
            float ghz = red[(3*12 + 4 + u2)*64 + b2] + red[(4*12 + 4 + u2)*64 + b2] + bhhl[4 + u2];
            float ghn = red[(3*12 + 8 + u2)*64 + b2] + red[(4*12 + 8 + u2)*64 + b2] + bhhl[8 + u2];
            float r = 1.f / (1.f + __expf(-(gir + ghr)));
            float z = 1.f / (1.f + __expf(-(giz + ghz)));
            float n = tanhf(gin + r * ghn);
            float hn = (1.f - z) * n + z * hloc[u2 * 64 + b2];
            hloc[u2 * 64 + b2] = hn;
            actg[(V3_HBASE + (par ^ 1) * 256 + wg * 4 + u2) * 64 + b2] = hn;
        }
        v3_gbar(flags, wg, ++gen);
    }
}

// ---- minimal fallback (one WG per batch) ----
__global__ __launch_bounds__(768) void rnn_fallback(
    const float* __restrict__ x, const float* __restrict__ mask,
    const float* __restrict__ W_ih, const float* __restrict__ W_hh,
    const float* __restrict__ b_ih, const float* __restrict__ b_hh,
    const float* __restrict__ W_ro, const float* __restrict__ b_ro,
    float* __restrict__ out)
{
    const int b = blockIdx.x, tid = threadIdx.x;
    __shared__ float h[HH];
    __shared__ float hnew[HH];
    __shared__ float xin[414 + 2];
    __shared__ float gi[768];
    __shared__ float gh[768];
    __shared__ float xhat[DD];
    const float bih = b_ih[tid], bhh = b_hh[tid];
    const float bro = (tid < DD) ? b_ro[tid] : 0.f;
    if (tid < HH) h[tid] = 0.f;
    if (tid < DD) xhat[tid] = bro;
    __syncthreads();
    const float* xb = x + (size_t)b * SS * DD;
    const float* mb = mask + (size_t)b * SS * DD;
    float* ob = out + (size_t)b * SS * DD;
    for (int t = 0; t < SS; ++t) {
        if (tid < DD) ob[t * DD + tid] = xhat[tid];
        if (t == SS - 1) break;
        if (tid < DD) {
            float m = mb[t * DD + tid], xv = xb[t * DD + tid];
            xin[tid] = (m > 0.5f) ? xv : xhat[tid];
            xin[DD + tid] = m;
        }
        __syncthreads();
        float accI = bih, accH = bhh;
        const float* wi = W_ih + (size_t)tid * 414;
        for (int k = 0; k < 414; ++k) accI += wi[k] * xin[k];
        const float* wh = W_hh + (size_t)tid * HH;
        for (int k = 0; k < HH; ++k) accH += wh[k] * h[k];
        gi[tid] = accI; gh[tid] = accH;
        __syncthreads();
        if (tid < HH) {
            float r = 1.f / (1.f + __expf(-(gi[tid] + gh[tid])));
            float z = 1.f / (1.f + __expf(-(gi[HH + tid] + gh[HH + tid])));
            float n = tanhf(gi[2 * HH + tid] + r * gh[2 * HH + tid]);
            hnew[tid] = (1.f - z) * n + z * h[tid];
        }
        __syncthreads();
        if (tid < DD) {
            float acc = bro;
            const float* wr = W_ro + (size_t)tid * HH;
            for (int k = 0; k < HH; ++k) acc += wr[k] * hnew[k];
            xhat[tid] = acc;
        }
        if (tid < HH) h[tid] = hnew[tid];
        __syncthreads();
    }
}

extern "C" void kernel_launch(void* const* d_in, const int* in_sizes, int n_in,
                              void* d_out, int out_size, void* d_ws, size_t ws_size,
                              hipStream_t stream) {
    const float* x    = (const float*)d_in[0];
    const float* mask = (const float*)d_in[1];
    const float* W_ih = (const float*)d_in[2];
    const float* W_hh = (const float*)d_in[3];
    const float* b_ih = (const float*)d_in[4];
    const float* b_hh = (const float*)d_in[5];
    const float* W_ro = (const float*)d_in[6];
    const float* b_ro = (const float*)d_in[7];
    float* out = (float*)d_out;
    float* ws  = (float*)d_ws;

    if (ws_size >= WS_NEED6) {
        hipLaunchKernelGGL(rnn_init10, dim3(64), dim3(256), 0, stream, ws);
        hipLaunchKernelGGL(rnn_persist10, dim3(NWG), dim3(512), 0, stream,
                           x, mask, W_ih, W_hh, b_ih, b_hh, W_ro, b_ro, ws, out);
        hipLaunchKernelGGL(out_transpose, dim3(SS), dim3(256), 0, stream,
                           ws + BUF_FLOATS + FLAG_U32, out);
    } else if (ws_size >= V3_WS_FULL) {
        hipLaunchKernelGGL(v3_init, dim3(32), dim3(256), 0, stream, ws);
        hipLaunchKernelGGL((v3_persist<true>), dim3(NWG), dim3(256), 0, stream,
                           x, mask, W_ih, W_hh, b_ih, b_hh, W_ro, b_ro, ws, out);
        hipLaunchKernelGGL(out_transpose, dim3(SS), dim3(256), 0, stream,
                           ws + V3_ACT + V3_FLAGS, out);
    } else if (ws_size >= V3_WS_SMALL) {
        hipLaunchKernelGGL(v3_init, dim3(32), dim3(256), 0, stream, ws);
        hipLaunchKernelGGL((v3_persist<false>), dim3(NWG), dim3(256), 0, stream,
                           x, mask, W_ih, W_hh, b_ih, b_hh, W_ro, b_ro, ws, out);
    } else {
        hipLaunchKernelGGL(rnn_fallback, dim3(BB), dim3(768), 0, stream,
                           x, mask, W_ih, W_hh, b_ih, b_hh, W_ro, b_ro, out);
    }
}

// Round 5
// 6696.899 us; speedup vs baseline: 1.0326x; 1.0326x over previous
//
#include <hip/hip_runtime.h>
#include <math.h>

#define BB 64
#define SS 512
#define DD 207
#define HH 256
#define NWG 64
#define LDW 676   // wgl row stride (%32==4 -> staggered banks)
#define ROW 260   // wrol row stride
#define AG __HIP_MEMORY_SCOPE_AGENT

// ================= v11: input-part pre-staging, short critical path ==========
// 64 WGs x 512 threads (8 waves, 2/SIMD — proven v7 occupancy).
// Algebra: gi = W_ih.[m*x; m] (input-only, PRE-STAGED) + W_x.((1-m)*xhat).
// Pre-stage kernel writes IN[t] = [m*x (207); m (207); 0 (2)] in [t][row][b]
// layout ONCE (read-only during persist -> no flag protocol for it).
// Per-step cross-WG exchanges (2 barriers, same as v7):
//   barrier_x: xhat_t  — published INTO stage (doubles as output buffer),
//              ast4/sc1, virgin rows per t, flag-gated.
//   barrier_h: h_{t+1} — published into HR[t+1] slots (virgin), as before.
// Step: [shadow: 416-row input GEMV] wait_h -> PhaseB -> publish xhat ->
//       arrive_x -> [shadow: gh 256] -> wait_x -> 207-row xhat GEMV
//       (reader masks with (1-m) from L1-hot IN rows) -> combine -> publish h.
// Critical-path GEMV shrinks 416->207 rows; shadows grow ~0.85 -> ~2.2 us.
// Workspace partition: IN 512x416x64 + HR 512x256x64 + stage 512x207x64
//   = (416+256+207)*64*512 = old (672+207)*64*512  -> WS_NEED unchanged.
#define IN_ROWS 416
#define IN_FLOATS ((size_t)SS * IN_ROWS * 64)       // 13,631,488
#define HR_FLOATS ((size_t)SS * HH * 64)            //  8,388,608
#define BUF_FLOATS (IN_FLOATS + HR_FLOATS)          // 22,020,096 == v7's BUF
#define FLAG_U32 (64 * 32)
#define STAGE_FLOATS ((size_t)SS * DD * 64)
#define WS_NEED6 ((BUF_FLOATS + FLAG_U32 + STAGE_FLOATS) * sizeof(float))

// ---- v3 fallback layout (round-3 proven path) ----
#define V3_AROWS 928
#define V3_HBASE 416
#define V3_ACT (V3_AROWS * 64)
#define V3_FLAGS (64 * 32)
#define V3_WS_SMALL ((size_t)(V3_ACT + V3_FLAGS) * sizeof(float))
#define V3_WS_FULL  ((size_t)(V3_ACT + V3_FLAGS + STAGE_FLOATS) * sizeof(float))

__device__ __forceinline__ void ast4(float* p, float v) {
    union { float f; unsigned u; } c; c.f = v;
    __hip_atomic_store((unsigned*)p, c.u, __ATOMIC_RELAXED, AG);
}

// 12-row (3 gates x unit u) GEMV partial, NORMAL float4 loads.
// A4 rows are 16 float4 wide; gr0 = row base, wc0 = weight col base (x4).
__device__ __forceinline__ void run_range6(
    const float4* __restrict__ A4, const float* __restrict__ wgl,
    float* __restrict__ red, int u, int bp, int wc0, int gr0, int len, int slot)
{
    float4 c0 = make_float4(0.f, 0.f, 0.f, 0.f);
    float4 c1 = c0, c2 = c0;
    #pragma unroll 4
    for (int k = 0; k < len; k += 4) {
        float4 a0 = A4[(gr0 + k + 0) * 16 + bp];
        float4 a1 = A4[(gr0 + k + 1) * 16 + bp];
        float4 a2 = A4[(gr0 + k + 2) * 16 + bp];
        float4 a3 = A4[(gr0 + k + 3) * 16 + bp];
        float4 w0 = *(const float4*)&wgl[(0 + u) * LDW + wc0 + k];
        float4 w1 = *(const float4*)&wgl[(4 + u) * LDW + wc0 + k];
        float4 w2 = *(const float4*)&wgl[(8 + u) * LDW + wc0 + k];
        c0.x += a0.x*w0.x + a1.x*w0.y + a2.x*w0.z + a3.x*w0.w;
        c0.y += a0.y*w0.x + a1.y*w0.y + a2.y*w0.z + a3.y*w0.w;
        c0.z += a0.z*w0.x + a1.z*w0.y + a2.z*w0.z + a3.z*w0.w;
        c0.w += a0.w*w0.x + a1.w*w0.y + a2.w*w0.z + a3.w*w0.w;
        c1.x += a0.x*w1.x + a1.x*w1.y + a2.x*w1.z + a3.x*w1.w;
        c1.y += a0.y*w1.x + a1.y*w1.y + a2.y*w1.z + a3.y*w1.w;
        c1.z += a0.z*w1.x + a1.z*w1.y + a2.z*w1.z + a3.z*w1.w;
        c1.w += a0.w*w1.x + a1.w*w1.y + a2.w*w1.z + a3.w*w1.w;
        c2.x += a0.x*w2.x + a1.x*w2.y + a2.x*w2.z + a3.x*w2.w;
        c2.y += a0.y*w2.x + a1.y*w2.y + a2.y*w2.z + a3.y*w2.w;
        c2.z += a0.z*w2.x + a1.z*w2.y + a2.z*w2.z + a3.z*w2.w;
        c2.w += a0.w*w2.x + a1.w*w2.y + a2.w*w2.z + a3.w*w2.w;
    }
    float4* R4 = (float4*)red;
    R4[(slot * 12 + 0 + u) * 16 + bp] = c0;
    R4[(slot * 12 + 4 + u) * 16 + bp] = c1;
    R4[(slot * 12 + 8 + u) * 16 + bp] = c2;
}

// xhat GEMV partial: a[d][b] = (1 - m[d][b]) * xhat[d][b]; rows r0..r0+nrow-1.
// S4 = stage as float4 (16/row), IN4 = IN as float4; mask rows at 207+d.
__device__ __forceinline__ void gemvX(
    const float4* __restrict__ S4, const float4* __restrict__ IN4,
    const float* __restrict__ wgl, float* __restrict__ red,
    int u, int bp, int t, int r0, int nrow, int slot)
{
    float4 c0 = make_float4(0.f, 0.f, 0.f, 0.f);
    float4 c1 = c0, c2 = c0;
    const int sb = t * DD + r0;
    const int mb = t * IN_ROWS + 207 + r0;
    int k = 0;
    for (; k + 4 <= nrow; k += 4) {
        float4 s0 = S4[(sb + k + 0) * 16 + bp];
        float4 s1 = S4[(sb + k + 1) * 16 + bp];
        float4 s2 = S4[(sb + k + 2) * 16 + bp];
        float4 s3 = S4[(sb + k + 3) * 16 + bp];
        float4 m0 = IN4[(mb + k + 0) * 16 + bp];
        float4 m1 = IN4[(mb + k + 1) * 16 + bp];
        float4 m2 = IN4[(mb + k + 2) * 16 + bp];
        float4 m3 = IN4[(mb + k + 3) * 16 + bp];
        float4 a0, a1, a2, a3;
        a0.x = fmaf(-m0.x, s0.x, s0.x); a0.y = fmaf(-m0.y, s0.y, s0.y);
        a0.z = fmaf(-m0.z, s0.z, s0.z); a0.w = fmaf(-m0.w, s0.w, s0.w);
        a1.x = fmaf(-m1.x, s1.x, s1.x); a1.y = fmaf(-m1.y, s1.y, s1.y);
        a1.z = fmaf(-m1.z, s1.z, s1.z); a1.w = fmaf(-m1.w, s1.w, s1.w);
        a2.x = fmaf(-m2.x, s2.x, s2.x); a2.y = fmaf(-m2.y, s2.y, s2.y);
        a2.z = fmaf(-m2.z, s2.z, s2.z); a2.w = fmaf(-m2.w, s2.w, s2.w);
        a3.x = fmaf(-m3.x, s3.x, s3.x); a3.y = fmaf(-m3.y, s3.y, s3.y);
        a3.z = fmaf(-m3.z, s3.z, s3.z); a3.w = fmaf(-m3.w, s3.w, s3.w);
        const int wc = r0 + k;
        float4 w0 = *(const float4*)&wgl[(0 + u) * LDW + wc];
        float4 w1 = *(const float4*)&wgl[(4 + u) * LDW + wc];
        float4 w2 = *(const float4*)&wgl[(8 + u) * LDW + wc];
        c0.x += a0.x*w0.x + a1.x*w0.y + a2.x*w0.z + a3.x*w0.w;
        c0.y += a0.y*w0.x + a1.y*w0.y + a2.y*w0.z + a3.y*w0.w;
        c0.z += a0.z*w0.x + a1.z*w0.y + a2.z*w0.z + a3.z*w0.w;
        c0.w += a0.w*w0.x + a1.w*w0.y + a2.w*w0.z + a3.w*w0.w;
        c1.x += a0.x*w1.x + a1.x*w1.y + a2.x*w1.z + a3.x*w1.w;
        c1.y += a0.y*w1.x + a1.y*w1.y + a2.y*w1.z + a3.y*w1.w;
        c1.z += a0.z*w1.x + a1.z*w1.y + a2.z*w1.z + a3.z*w1.w;
        c1.w += a0.w*w1.x + a1.w*w1.y + a2.w*w1.z + a3.w*w1.w;
        c2.x += a0.x*w2.x + a1.x*w2.y + a2.x*w2.z + a3.x*w2.w;
        c2.y += a0.y*w2.x + a1.y*w2.y + a2.y*w2.z + a3.y*w2.w;
        c2.z += a0.z*w2.x + a1.z*w2.y + a2.z*w2.z + a3.z*w2.w;
        c2.w += a0.w*w2.x + a1.w*w2.y + a2.w*w2.z + a3.w*w2.w;
    }
    for (; k < nrow; ++k) {
        float4 s = S4[(sb + k) * 16 + bp];
        float4 m = IN4[(mb + k) * 16 + bp];
        float4 a;
        a.x = fmaf(-m.x, s.x, s.x); a.y = fmaf(-m.y, s.y, s.y);
        a.z = fmaf(-m.z, s.z, s.z); a.w = fmaf(-m.w, s.w, s.w);
        float w0 = wgl[(0 + u) * LDW + r0 + k];
        float w1 = wgl[(4 + u) * LDW + r0 + k];
        float w2 = wgl[(8 + u) * LDW + r0 + k];
        c0.x += a.x*w0; c0.y += a.y*w0; c0.z += a.z*w0; c0.w += a.w*w0;
        c1.x += a.x*w1; c1.y += a.y*w1; c1.z += a.z*w1; c1.w += a.w*w1;
        c2.x += a.x*w2; c2.y += a.y*w2; c2.z += a.z*w2; c2.w += a.w*w2;
    }
    float4* R4 = (float4*)red;
    R4[(slot * 12 + 0 + u) * 16 + bp] = c0;
    R4[(slot * 12 + 4 + u) * 16 + bp] = c1;
    R4[(slot * 12 + 8 + u) * 16 + bp] = c2;
}

// pre-stage kernel: IN[t] = [m*x (rows 0..206); m (rows 207..413); 0 (414/415)]
__global__ __launch_bounds__(256) void stage_inputs(
    const float* __restrict__ x, const float* __restrict__ mask,
    float* __restrict__ ws)
{
    __shared__ float lds[DD * 65];
    const int t = blockIdx.x;
    float* IN = ws;
    // pass 1: masked x
    for (int i = threadIdx.x; i < DD * 64; i += 256) {
        int b = i / DD, d = i - b * DD;
        size_t g = (size_t)b * (SS * DD) + (size_t)t * DD + d;
        float xv = x[g], mv = mask[g];
        lds[d * 65 + b] = (mv > 0.5f) ? xv : 0.f;
    }
    __syncthreads();
    for (int i = threadIdx.x; i < DD * 64; i += 256) {
        int d = i >> 6, b = i & 63;
        IN[((size_t)t * IN_ROWS + d) * 64 + b] = lds[d * 65 + b];
    }
    __syncthreads();
    // pass 2: mask
    for (int i = threadIdx.x; i < DD * 64; i += 256) {
        int b = i / DD, d = i - b * DD;
        lds[d * 65 + b] = mask[(size_t)b * (SS * DD) + (size_t)t * DD + d];
    }
    __syncthreads();
    for (int i = threadIdx.x; i < DD * 64; i += 256) {
        int d = i >> 6, b = i & 63;
        IN[((size_t)t * IN_ROWS + 207 + d) * 64 + b] = lds[d * 65 + b];
    }
    // zero pad rows 414/415
    for (int i = threadIdx.x; i < 2 * 64; i += 256)
        IN[((size_t)t * IN_ROWS + 414) * 64 + i] = 0.f;
}

__global__ __launch_bounds__(256) void rnn_init11(float* __restrict__ ws) {
    int i = blockIdx.x * blockDim.x + threadIdx.x;
    // zero HR[0] (h_0 = 0)
    for (int idx = i; idx < HH * 64; idx += gridDim.x * blockDim.x)
        ws[IN_FLOATS + idx] = 0.f;
    unsigned* fl = (unsigned*)(ws + BUF_FLOATS);
    for (int idx = i; idx < FLAG_U32; idx += gridDim.x * blockDim.x)
        fl[idx] = 0u;
}

__global__ __launch_bounds__(512) void rnn_persist11(
    const float* __restrict__ x, const float* __restrict__ mask,
    const float* __restrict__ W_ih, const float* __restrict__ W_hh,
    const float* __restrict__ b_ih, const float* __restrict__ b_hh,
    const float* __restrict__ W_ro, const float* __restrict__ b_ro,
    float* __restrict__ ws, float* __restrict__ out)
{
    const int wg = blockIdx.x;
    const int tid = threadIdx.x;
    const int lane = tid & 63;
    const int wv = tid >> 6;            // 0..7

    float* INf = ws;
    float* HRf = ws + IN_FLOATS;
    unsigned* flags = (unsigned*)(ws + BUF_FLOATS);
    float* stage = ws + BUF_FLOATS + FLAG_U32;

    const float4* IN4 = (const float4*)INf;
    const float4* HR4 = (const float4*)HRf;
    const float4* S4  = (const float4*)stage;

    __shared__ float wgl[12 * LDW];      // 12 gate rows x 676 (414/415 = 0)
    __shared__ float wrol[4 * ROW];      // up to 4 readout rows
    __shared__ float red[24 * 12 * 64];  // slots 0-7 input, 8-15 gh, 16-23 xhat
    __shared__ float redB[32 * 64];      // readout partials (8 waves x 4 rows)
    __shared__ float hloc[4 * 64];       // own hidden units
    __shared__ float bihl[12], bhhl[12], brol[4];

    const int d0 = (207 * wg) / NWG;
    const int d1 = (207 * (wg + 1)) / NWG;
    const int dc = d1 - d0;

    for (int i = tid; i < 12 * LDW; i += 512) {
        int r = i / LDW, c = i - r * LDW;
        int rg = (r >> 2) * 256 + wg * 4 + (r & 3);
        float v = 0.f;
        if (c < 414) v = W_ih[rg * 414 + c];
        else if (c >= 416 && c < 672) v = W_hh[rg * 256 + (c - 416)];
        wgl[i] = v;
    }
    for (int i = tid; i < 4 * 256; i += 512) {
        int dl_ = i >> 8, j = i & 255;
        wrol[dl_ * ROW + j] = (dl_ < dc) ? W_ro[(d0 + dl_) * 256 + j] : 0.f;
    }
    if (tid < 12) {
        int rg = (tid >> 2) * 256 + wg * 4 + (tid & 3);
        bihl[tid] = b_ih[rg];
        bhhl[tid] = b_hh[rg];
    }
    if (tid < 4) brol[tid] = (tid < dc) ? b_ro[d0 + tid] : 0.f;
    if (tid < 256) hloc[tid] = 0.f;
    __syncthreads();

    const int u  = lane >> 4;
    const int bp = lane & 15;

    const bool have = (tid < dc * 64);
    const int dl = tid >> 6, b = tid & 63;

    // xhat GEMV split: waves 0-6 -> 28 rows, wave 7 -> 11 (r0 stays x4-aligned)
    const int xr0  = wv * 28;
    const int xlen = (wv < 7) ? 28 : 11;

    unsigned genX = 0, genH = 0;

    for (int t = 0; t < SS; ++t) {
        // ---- (A) shadow: input-only GEMV from IN[t] (covers barrier_h prop) ----
        if (t < SS - 1)
            run_range6(IN4, wgl, red, u, bp, wv * 52,
                       t * IN_ROWS + wv * 52, 52, wv);

        // ---- (B) wait_h: HR[t] ready ----
        if (tid < 64) {
            unsigned* f = &flags[tid * 32 + 8];
            while (__hip_atomic_load(f, __ATOMIC_RELAXED, AG) < genH) {}
        }
        __syncthreads();

        // ---- (C) Phase B: readout partials from h_t (virgin cached reads) ----
        {
            const float* hrow = HRf + (size_t)t * HH * 64;
            const int jb = wv * 32;
            float acc0 = 0.f, acc1 = 0.f, acc2 = 0.f, acc3 = 0.f;
            #pragma unroll 4
            for (int j = 0; j < 32; j += 4) {
                float a0 = hrow[(jb + j + 0) * 64 + lane];
                float a1 = hrow[(jb + j + 1) * 64 + lane];
                float a2 = hrow[(jb + j + 2) * 64 + lane];
                float a3 = hrow[(jb + j + 3) * 64 + lane];
                float4 w0 = *(const float4*)&wrol[0 * ROW + jb + j];
                float4 w1 = *(const float4*)&wrol[1 * ROW + jb + j];
                float4 w2 = *(const float4*)&wrol[2 * ROW + jb + j];
                float4 w3 = *(const float4*)&wrol[3 * ROW + jb + j];
                acc0 += a0*w0.x + a1*w0.y + a2*w0.z + a3*w0.w;
                acc1 += a0*w1.x + a1*w1.y + a2*w1.z + a3*w1.w;
                acc2 += a0*w2.x + a1*w2.y + a2*w2.z + a3*w2.w;
                acc3 += a0*w3.x + a1*w3.y + a2*w3.z + a3*w3.w;
            }
            redB[(wv * 4 + 0) * 64 + lane] = acc0;
            redB[(wv * 4 + 1) * 64 + lane] = acc1;
            redB[(wv * 4 + 2) * 64 + lane] = acc2;
            redB[(wv * 4 + 3) * 64 + lane] = acc3;
        }
        __syncthreads();

        // ---- (D) xh combine; publish xhat into stage (sc1; exchange+output) ----
        if (have) {
            float xh = brol[dl];
            #pragma unroll
            for (int g = 0; g < 8; ++g)
                xh += redB[(g * 4 + dl) * 64 + b];
            ast4(&stage[((size_t)t * DD + d0 + dl) * 64 + b], xh);
        }
        if (t == SS - 1) break;

        // ---- (E) arrive_x ----
        ++genX;
        asm volatile("s_waitcnt vmcnt(0)" ::: "memory");
        __syncthreads();
        if (tid == 0)
            __hip_atomic_store(&flags[wg * 32 + 0], genX, __ATOMIC_RELAXED, AG);

        // ---- (F) shadow: gh from HR[t] (L1/L2-hot; covers barrier_x prop) ----
        run_range6(HR4, wgl, red, u, bp, 416 + wv * 32,
                   t * HH + wv * 32, 32, 8 + wv);

        // ---- (G) wait_x ----
        if (tid < 64) {
            unsigned* f = &flags[tid * 32 + 0];
            while (__hip_atomic_load(f, __ATOMIC_RELAXED, AG) < genX) {}
        }
        __syncthreads();

        // ---- (H) critical: xhat GEMV (207 rows, reader-masked) ----
        gemvX(S4, IN4, wgl, red, u, bp, t, xr0, xlen, 16 + wv);
        __syncthreads();

        // ---- (I) combine + gates + publish h_{t+1} into HR[t+1] (sc1) ----
        if (tid < 256) {
            const int u2 = tid >> 6, b2 = tid & 63;
            float gir = bihl[0 + u2], giz = bihl[4 + u2], gin = bihl[8 + u2];
            float ghr = bhhl[0 + u2], ghz = bhhl[4 + u2], ghn = bhhl[8 + u2];
            #pragma unroll
            for (int s = 0; s < 8; ++s) {
                gir += red[(s * 12 + 0 + u2) * 64 + b2]
                     + red[((16 + s) * 12 + 0 + u2) * 64 + b2];
                giz += red[(s * 12 + 4 + u2) * 64 + b2]
                     + red[((16 + s) * 12 + 4 + u2) * 64 + b2];
                gin += red[(s * 12 + 8 + u2) * 64 + b2]
                     + red[((16 + s) * 12 + 8 + u2) * 64 + b2];
                ghr += red[((8 + s) * 12 + 0 + u2) * 64 + b2];
                ghz += red[((8 + s) * 12 + 4 + u2) * 64 + b2];
                ghn += red[((8 + s) * 12 + 8 + u2) * 64 + b2];
            }
            float r = 1.f / (1.f + __expf(-(gir + ghr)));
            float z = 1.f / (1.f + __expf(-(giz + ghz)));
            float n = tanhf(gin + r * ghn);
            float hn = (1.f - z) * n + z * hloc[u2 * 64 + b2];
            hloc[u2 * 64 + b2] = hn;
            ast4(&HRf[((size_t)(t + 1) * HH + wg * 4 + u2) * 64 + b2], hn);
        }

        // ---- (J) arrive_h ----
        ++genH;
        asm volatile("s_waitcnt vmcnt(0)" ::: "memory");
        __syncthreads();
        if (tid == 0)
            __hip_atomic_store(&flags[wg * 32 + 8], genH, __ATOMIC_RELAXED, AG);
        // loop top's input GEMV for t+1 is the shadow covering this barrier
    }
}

// epilogue: stage[t][d][b] -> out[b][t][d]
__global__ __launch_bounds__(256) void out_transpose(
    const float* __restrict__ stage, float* __restrict__ out)
{
    __shared__ float lds[DD * 65];
    const int t = blockIdx.x;
    const float* st = stage + (size_t)t * DD * 64;
    for (int i = threadIdx.x; i < DD * 64; i += 256) {
        int d = i >> 6, b = i & 63;
        lds[d * 65 + b] = st[i];
    }
    __syncthreads();
    for (int i = threadIdx.x; i < DD * 64; i += 256) {
        int b = i / DD, d = i - b * DD;
        out[(size_t)b * (SS * DD) + (size_t)t * DD + d] = lds[d * 65 + b];
    }
}

// ================= v3 middle fallback (round-3 proven, 8.1 ms) =================
__device__ __forceinline__ void v3_gbar(unsigned* flags, int wg, unsigned g) {
    __syncthreads();
    if (threadIdx.x < 64) {
        if (threadIdx.x == 0) {
            __builtin_amdgcn_fence(__ATOMIC_RELEASE, "agent");
            __hip_atomic_store(&flags[wg * 32], g, __ATOMIC_RELAXED, AG);
        }
        unsigned* f = &flags[threadIdx.x * 32];
        while (__hip_atomic_load(f, __ATOMIC_RELAXED, AG) < g) { }
        __builtin_amdgcn_fence(__ATOMIC_ACQUIRE, "agent");
    }
    __syncthreads();
}

__global__ __launch_bounds__(256) void v3_init(float* __restrict__ ws) {
    int i = blockIdx.x * blockDim.x + threadIdx.x;
    const int nz = (672 - 414) * 64;
    for (int idx = i; idx < nz; idx += gridDim.x * blockDim.x)
        ws[414 * 64 + idx] = 0.f;
    for (int idx = i; idx < V3_FLAGS; idx += gridDim.x * blockDim.x)
        ((unsigned*)(ws + V3_ACT))[idx] = 0u;
}

template<bool STAGE>
__global__ __launch_bounds__(256) void v3_persist(
    const float* __restrict__ x, const float* __restrict__ mask,
    const float* __restrict__ W_ih, const float* __restrict__ W_hh,
    const float* __restrict__ b_ih, const float* __restrict__ b_hh,
    const float* __restrict__ W_ro, const float* __restrict__ b_ro,
    float* __restrict__ ws, float* __restrict__ out)
{
    const int wg = blockIdx.x;
    const int tid = threadIdx.x;
    const int lane = tid & 63;
    const int wv = tid >> 6;

    float* actg = ws;
    unsigned* flags = (unsigned*)(ws + V3_ACT);
    float* stage = ws + V3_ACT + V3_FLAGS;

    __shared__ float wgl[12 * LDW];
    __shared__ float wrol[4 * 256];
    __shared__ float red[5 * 12 * 64];
    __shared__ float redB[16 * 64];
    __shared__ float hloc[4 * 64];
    __shared__ float bihl[12], bhhl[12], brol[4];

    const int d0 = (207 * wg) / NWG;
    const int d1 = (207 * (wg + 1)) / NWG;
    const int dc = d1 - d0;

    for (int i = tid; i < 12 * LDW; i += 256) {
        int r = i / LDW, c = i - r * LDW;
        int rg = (r >> 2) * 256 + wg * 4 + (r & 3);
        float v = 0.f;
        if (c < 414) v = W_ih[rg * 414 + c];
        else if (c >= 416 && c < 672) v = W_hh[rg * 256 + (c - 416)];
        wgl[i] = v;
    }
    for (int i = tid; i < 4 * 256; i += 256) {
        int dl_ = i >> 8, j = i & 255;
        wrol[i] = (dl_ < dc) ? W_ro[(d0 + dl_) * 256 + j] : 0.f;
    }
    if (tid < 12) {
        int rg = (tid >> 2) * 256 + wg * 4 + (tid & 3);
        bihl[tid] = b_ih[rg];
        bhhl[tid] = b_hh[rg];
    }
    if (tid < 4) brol[tid] = (tid < dc) ? b_ro[d0 + tid] : 0.f;
    hloc[tid] = 0.f;
    __syncthreads();

    const float4* A4 = (const float4*)actg;
    const int u = lane >> 4;
    const int bp = lane & 15;

    const bool have = (tid < dc * 64);
    const int dl = tid >> 6, b = tid & 63;
    const size_t gbase = (size_t)b * (SS * DD) + (d0 + dl);
    float xv_pf = 0.f, mv_pf = 0.f;
    if (have) { xv_pf = x[gbase]; mv_pf = mask[gbase]; }

    unsigned gen = 0;

    for (int t = 0; t < SS; ++t) {
        const int par = t & 1;
        const int hrow0 = V3_HBASE + par * 256;

        {
            const float* hrow = actg + hrow0 * 64;
            const int jb = wv * 64;
            float acc0 = 0.f, acc1 = 0.f, acc2 = 0.f, acc3 = 0.f;
            #pragma unroll 4
            for (int j = 0; j < 64; j += 4) {
                float a0 = hrow[(jb + j + 0) * 64 + lane];
                float a1 = hrow[(jb + j + 1) * 64 + lane];
                float a2 = hrow[(jb + j + 2) * 64 + lane];
                float a3 = hrow[(jb + j + 3) * 64 + lane];
                float4 w0 = *(const float4*)&wrol[0 * 256 + jb + j];
                float4 w1 = *(const float4*)&wrol[1 * 256 + jb + j];
                float4 w2 = *(const float4*)&wrol[2 * 256 + jb + j];
                float4 w3 = *(const float4*)&wrol[3 * 256 + jb + j];
                acc0 += a0*w0.x + a1*w0.y + a2*w0.z + a3*w0.w;
                acc1 += a0*w1.x + a1*w1.y + a2*w1.z + a3*w1.w;
                acc2 += a0*w2.x + a1*w2.y + a2*w2.z + a3*w2.w;
                acc3 += a0*w3.x + a1*w3.y + a2*w3.z + a3*w3.w;
            }
            redB[(wv * 4 + 0) * 64 + lane] = acc0;
            redB[(wv * 4 + 1) * 64 + lane] = acc1;
            redB[(wv * 4 + 2) * 64 + lane] = acc2;
            redB[(wv * 4 + 3) * 64 + lane] = acc3;
        }
        __syncthreads();
        if (have) {
            float xh = redB[(0 * 4 + dl) * 64 + b] + redB[(1 * 4 + dl) * 64 + b]
                     + redB[(2 * 4 + dl) * 64 + b] + redB[(3 * 4 + dl) * 64 + b]
                     + brol[dl];
            if (STAGE) stage[(t * DD + d0 + dl) * 64 + b] = xh;
            else       out[gbase + (size_t)t * DD] = xh;
            if (t < SS - 1) {
                float xi = (mv_pf > 0.5f) ? xv_pf : xh;
                actg[(d0 + dl) * 64 + b] = xi;
                actg[(207 + d0 + dl) * 64 + b] = mv_pf;
            }
        }
        if (t == SS - 1) break;

        if (have && t + 1 < SS - 1) {
            xv_pf = x[gbase + (size_t)(t + 1) * DD];
            mv_pf = mask[gbase + (size_t)(t + 1) * DD];
        }

        v3_gbar(flags, wg, ++gen);

        if (wv == 0)      run_range6(A4, wgl, red, u, bp, 0,   0,          168, 0);
        else if (wv == 1) run_range6(A4, wgl, red, u, bp, 168, 168,        168, 1);
        else if (wv == 2) {
            run_range6(A4, wgl, red, u, bp, 336, 336,        80,  2);
            run_range6(A4, wgl, red, u, bp, 416, hrow0,      96,  3);
        } else            run_range6(A4, wgl, red, u, bp, 512, hrow0 + 96, 160, 4);
        __syncthreads();
        {
            const int u2 = tid >> 6, b2 = tid & 63;
            float gir = red[(0*12 + 0 + u2)*64 + b2] + red[(1*12 + 0 + u2)*64 + b2]
                      + red[(2*12 + 0 + u2)*64 + b2] + bihl[0 + u2];
            float giz = red[(0*12 + 4 + u2)*64 + b2] + red[(1*12 + 4 + u2)*64 + b2]
                      + red[(2*12 + 4 + u2)*64 + b2] + bihl[4 + u2];
            float gin = red[(0*12 + 8 + u2)*64 + b2] + red[(1*12 + 8 + u2)*64 + b2]
                      + red[(2*12 + 8 + u2)*64 + b2] + bihl[8 + u2];
            float ghr = red[(3*12 + 0 + u2)*64 + b2] + red[(4*12 + 0 + u2)*64 + b2] + bhhl[0 + u2];
            float ghz = red[(3*12 + 4 + u2)*64 + b2] + red[(4*12 + 4 + u2)*64 + b2] + bhhl[4 + u2];
            float ghn = red[(3*12 + 8 + u2)*64 + b2] + red[(4*12 + 8 + u2)*64 + b2] + bhhl[8 + u2];
            float r = 1.f / (1.f + __expf(-(gir + ghr)));
            float z = 1.f / (1.f + __expf(-(giz + ghz)));
            float n = tanhf(gin + r * ghn);
            float hn = (1.f - z) * n + z * hloc[u2 * 64 + b2];
            hloc[u2 * 64 + b2] = hn;
            actg[(V3_HBASE + (par ^ 1) * 256 + wg * 4 + u2) * 64 + b2] = hn;
        }
        v3_gbar(flags, wg, ++gen);
    }
}

// ---- minimal fallback (one WG per batch) ----
__global__ __launch_bounds__(768) void rnn_fallback(
    const float* __restrict__ x, const float* __restrict__ mask,
    const float* __restrict__ W_ih, const float* __restrict__ W_hh,
    const float* __restrict__ b_ih, const float* __restrict__ b_hh,
    const float* __restrict__ W_ro, const float* __restrict__ b_ro,
    float* __restrict__ out)
{
    const int b = blockIdx.x, tid = threadIdx.x;
    __shared__ float h[HH];
    __shared__ float hnew[HH];
    __shared__ float xin[414 + 2];
    __shared__ float gi[768];
    __shared__ float gh[768];
    __shared__ float xhat[DD];
    const float bih = b_ih[tid], bhh = b_hh[tid];
    const float bro = (tid < DD) ? b_ro[tid] : 0.f;
    if (tid < HH) h[tid] = 0.f;
    if (tid < DD) xhat[tid] = bro;
    __syncthreads();
    const float* xb = x + (size_t)b * SS * DD;
    const float* mb = mask + (size_t)b * SS * DD;
    float* ob = out + (size_t)b * SS * DD;
    for (int t = 0; t < SS; ++t) {
        if (tid < DD) ob[t * DD + tid] = xhat[tid];
        if (t == SS - 1) break;
        if (tid < DD) {
            float m = mb[t * DD + tid], xv = xb[t * DD + tid];
            xin[tid] = (m > 0.5f) ? xv : xhat[tid];
            xin[DD + tid] = m;
        }
        __syncthreads();
        float accI = bih, accH = bhh;
        const float* wi = W_ih + (size_t)tid * 414;
        for (int k = 0; k < 414; ++k) accI += wi[k] * xin[k];
        const float* wh = W_hh + (size_t)tid * HH;
        for (int k = 0; k < HH; ++k) accH += wh[k] * h[k];
        gi[tid] = accI; gh[tid] = accH;
        __syncthreads();
        if (tid < HH) {
            float r = 1.f / (1.f + __expf(-(gi[tid] + gh[tid])));
            float z = 1.f / (1.f + __expf(-(gi[HH + tid] + gh[HH + tid])));
            float n = tanhf(gi[2 * HH + tid] + r * gh[2 * HH + tid]);
            hnew[tid] = (1.f - z) * n + z * h[tid];
        }
        __syncthreads();
        if (tid < DD) {
            float acc = bro;
            const float* wr = W_ro + (size_t)tid * HH;
            for (int k = 0; k < HH; ++k) acc += wr[k] * hnew[k];
            xhat[tid] = acc;
        }
        if (tid < HH) h[tid] = hnew[tid];
        __syncthreads();
    }
}

extern "C" void kernel_launch(void* const* d_in, const int* in_sizes, int n_in,
                              void* d_out, int out_size, void* d_ws, size_t ws_size,
                              hipStream_t stream) {
    const float* x    = (const float*)d_in[0];
    const float* mask = (const float*)d_in[1];
    const float* W_ih = (const float*)d_in[2];
    const float* W_hh = (const float*)d_in[3];
    const float* b_ih = (const float*)d_in[4];
    const float* b_hh = (const float*)d_in[5];
    const float* W_ro = (const float*)d_in[6];
    const float* b_ro = (const float*)d_in[7];
    float* out = (float*)d_out;
    float* ws  = (float*)d_ws;

    if (ws_size >= WS_NEED6) {
        hipLaunchKernelGGL(stage_inputs, dim3(SS), dim3(256), 0, stream,
                           x, mask, ws);
        hipLaunchKernelGGL(rnn_init11, dim3(64), dim3(256), 0, stream, ws);
        hipLaunchKernelGGL(rnn_persist11, dim3(NWG), dim3(512), 0, stream,
                           x, mask, W_ih, W_hh, b_ih, b_hh, W_ro, b_ro, ws, out);
        hipLaunchKernelGGL(out_transpose, dim3(SS), dim3(256), 0, stream,
                           ws + BUF_FLOATS + FLAG_U32, out);
    } else if (ws_size >= V3_WS_FULL) {
        hipLaunchKernelGGL(v3_init, dim3(32), dim3(256), 0, stream, ws);
        hipLaunchKernelGGL((v3_persist<true>), dim3(NWG), dim3(256), 0, stream,
                           x, mask, W_ih, W_hh, b_ih, b_hh, W_ro, b_ro, ws, out);
        hipLaunchKernelGGL(out_transpose, dim3(SS), dim3(256), 0, stream,
                           ws + V3_ACT + V3_FLAGS, out);
    } else if (ws_size >= V3_WS_SMALL) {
        hipLaunchKernelGGL(v3_init, dim3(32), dim3(256), 0, stream, ws);
        hipLaunchKernelGGL((v3_persist<false>), dim3(NWG), dim3(256), 0, stream,
                           x, mask, W_ih, W_hh, b_ih, b_hh, W_ro, b_ro, ws, out);
    } else {
        hipLaunchKernelGGL(rnn_fallback, dim3(BB), dim3(768), 0, stream,
                           x, mask, W_ih, W_hh, b_ih, b_hh, W_ro, b_ro, out);
    }
}

// Round 6
// 6009.203 us; speedup vs baseline: 1.1508x; 1.1144x over previous
//
#include <hip/hip_runtime.h>
#include <math.h>

#define BB 64
#define SS 512
#define DD 207
#define HH 256
#define NWG 64
#define LDW 676   // wgl row stride (%32==4 -> staggered banks)
#define ROW 260   // wrol row stride
#define AG __HIP_MEMORY_SCOPE_AGENT

// ================= v12: v7 + mask-GEMV off the critical path =================
// 64 WGs x 512 threads (8 waves, 2/SIMD — proven v7 occupancy). Identical
// protocol/layout to v7 (step-slot rotation, sc1 publishes, virgin cached
// reads, monotone flags). Changes:
//  * mask rows (207..413) of slot t+2 are published in the barrier-2 shadow
//    (depth-2 pipeline; drained by the NEXT arr1's vmcnt -> readers, who only
//    touch them after the matching wait1, are race-free). Slots 0,1 in-band.
//  * the mask-part GEMV (rows 208..415, W cols incl. zero pads) runs in the
//    barrier-2 shadow of step t-1 into red slots 16-23 (zero-initialized;
//    combine reads them BEFORE the next shadow overwrites -> single bank ok).
//  * the post-wait1 CRITICAL GEMV covers only rows 0..207 (x_p + mask col 0):
//    critical-path loads halve (52 -> 26 rows/wave).
//  * steps t<2 use the v7 full-416-row critical path (slots 16-23 still zero).
#define SROWS 672
#define HOFF  416
#define SLOT  (SROWS * 64)
#define BUF_FLOATS ((size_t)SS * SLOT)
#define FLAG_U32 (64 * 32)
#define STAGE_FLOATS ((size_t)SS * DD * 64)
#define WS_NEED6 ((BUF_FLOATS + FLAG_U32 + STAGE_FLOATS) * sizeof(float))

// ---- v3 fallback layout (round-3 proven path) ----
#define V3_AROWS 928
#define V3_HBASE 416
#define V3_ACT (V3_AROWS * 64)
#define V3_FLAGS (64 * 32)
#define V3_WS_SMALL ((size_t)(V3_ACT + V3_FLAGS) * sizeof(float))
#define V3_WS_FULL  ((size_t)(V3_ACT + V3_FLAGS + STAGE_FLOATS) * sizeof(float))

__device__ __forceinline__ void ast4(float* p, float v) {
    union { float f; unsigned u; } c; c.f = v;
    __hip_atomic_store((unsigned*)p, c.u, __ATOMIC_RELAXED, AG);
}

// 12-row (3 gates x unit u) GEMV partial, NORMAL float4 loads (round-3 shape).
// gr0 = global float4-row base (t*672 + local row), wc0 = weight col base.
__device__ __forceinline__ void run_range6(
    const float4* __restrict__ A4, const float* __restrict__ wgl,
    float* __restrict__ red, int u, int bp, int wc0, int gr0, int len, int slot)
{
    float4 c0 = make_float4(0.f, 0.f, 0.f, 0.f);
    float4 c1 = c0, c2 = c0;
    #pragma unroll 4
    for (int k = 0; k < len; k += 4) {
        float4 a0 = A4[(gr0 + k + 0) * 16 + bp];
        float4 a1 = A4[(gr0 + k + 1) * 16 + bp];
        float4 a2 = A4[(gr0 + k + 2) * 16 + bp];
        float4 a3 = A4[(gr0 + k + 3) * 16 + bp];
        float4 w0 = *(const float4*)&wgl[(0 + u) * LDW + wc0 + k];
        float4 w1 = *(const float4*)&wgl[(4 + u) * LDW + wc0 + k];
        float4 w2 = *(const float4*)&wgl[(8 + u) * LDW + wc0 + k];
        c0.x += a0.x*w0.x + a1.x*w0.y + a2.x*w0.z + a3.x*w0.w;
        c0.y += a0.y*w0.x + a1.y*w0.y + a2.y*w0.z + a3.y*w0.w;
        c0.z += a0.z*w0.x + a1.z*w0.y + a2.z*w0.z + a3.z*w0.w;
        c0.w += a0.w*w0.x + a1.w*w0.y + a2.w*w0.z + a3.w*w0.w;
        c1.x += a0.x*w1.x + a1.x*w1.y + a2.x*w1.z + a3.x*w1.w;
        c1.y += a0.y*w1.x + a1.y*w1.y + a2.y*w1.z + a3.y*w1.w;
        c1.z += a0.z*w1.x + a1.z*w1.y + a2.z*w1.z + a3.z*w1.w;
        c1.w += a0.w*w1.x + a1.w*w1.y + a2.w*w1.z + a3.w*w1.w;
        c2.x += a0.x*w2.x + a1.x*w2.y + a2.x*w2.z + a3.x*w2.w;
        c2.y += a0.y*w2.x + a1.y*w2.y + a2.y*w2.z + a3.y*w2.w;
        c2.z += a0.z*w2.x + a1.z*w2.y + a2.z*w2.z + a3.z*w2.w;
        c2.w += a0.w*w2.x + a1.w*w2.y + a2.w*w2.z + a3.w*w2.w;
    }
    float4* R4 = (float4*)red;
    R4[(slot * 12 + 0 + u) * 16 + bp] = c0;
    R4[(slot * 12 + 4 + u) * 16 + bp] = c1;
    R4[(slot * 12 + 8 + u) * 16 + bp] = c2;
}

__global__ __launch_bounds__(256) void rnn_init6(float* __restrict__ ws) {
    int i = blockIdx.x * blockDim.x + threadIdx.x;
    // zero slot-0 h rows (h_0 = 0)
    for (int idx = i; idx < HH * 64; idx += gridDim.x * blockDim.x)
        ws[HOFF * 64 + idx] = 0.f;
    unsigned* fl = (unsigned*)(ws + BUF_FLOATS);
    for (int idx = i; idx < FLAG_U32; idx += gridDim.x * blockDim.x)
        fl[idx] = 0u;
}

__global__ __launch_bounds__(512) void rnn_persist12(
    const float* __restrict__ x, const float* __restrict__ mask,
    const float* __restrict__ W_ih, const float* __restrict__ W_hh,
    const float* __restrict__ b_ih, const float* __restrict__ b_hh,
    const float* __restrict__ W_ro, const float* __restrict__ b_ro,
    float* __restrict__ ws, float* __restrict__ out)
{
    const int wg = blockIdx.x;
    const int tid = threadIdx.x;
    const int lane = tid & 63;
    const int wv = tid >> 6;          // 0..7

    float* buf = ws;
    unsigned* flags = (unsigned*)(ws + BUF_FLOATS);
    float* stage = ws + BUF_FLOATS + FLAG_U32;

    __shared__ float wgl[12 * LDW];      // 12 gate rows x 676 (cols 414/415 = 0)
    __shared__ float wrol[4 * ROW];      // up to 4 readout rows
    __shared__ float red[24 * 12 * 64];  // 0-7 critical, 8-15 gh, 16-23 mask
    __shared__ float redB[32 * 64];      // readout partials (8 waves x 4 rows)
    __shared__ float hloc[4 * 64];       // own hidden units
    __shared__ float bihl[12], bhhl[12], brol[4];

    const int d0 = (207 * wg) / NWG;
    const int d1 = (207 * (wg + 1)) / NWG;
    const int dc = d1 - d0;

    for (int i = tid; i < 12 * LDW; i += 512) {
        int r = i / LDW, c = i - r * LDW;
        int rg = (r >> 2) * 256 + wg * 4 + (r & 3);
        float v = 0.f;
        if (c < 414) v = W_ih[rg * 414 + c];
        else if (c >= 416 && c < 672) v = W_hh[rg * 256 + (c - 416)];
        wgl[i] = v;
    }
    for (int i = tid; i < 4 * 256; i += 512) {
        int dl_ = i >> 8, j = i & 255;
        wrol[dl_ * ROW + j] = (dl_ < dc) ? W_ro[(d0 + dl_) * 256 + j] : 0.f;
    }
    if (tid < 12) {
        int rg = (tid >> 2) * 256 + wg * 4 + (tid & 3);
        bihl[tid] = b_ih[rg];
        bhhl[tid] = b_hh[rg];
    }
    if (tid < 4) brol[tid] = (tid < dc) ? b_ro[d0 + tid] : 0.f;
    if (tid < 256) hloc[tid] = 0.f;
    // zero mask-GEMV slots 16-23 (read by combine at t<2 before first write)
    for (int i = tid; i < 8 * 12 * 64; i += 512)
        red[16 * 12 * 64 + i] = 0.f;
    __syncthreads();

    const float4* A4 = (const float4*)buf;
    const int u  = lane >> 4;
    const int bp = lane & 15;

    const bool have = (tid < dc * 64);
    const int dl = tid >> 6, b = tid & 63;
    const size_t gbase = (size_t)b * (SS * DD) + (d0 + dl);

    // depth-2 input pipeline: (xva,mva) = step t, (xvb,mvb) = step t+1
    float xva = 0.f, mva = 0.f, xvb = 0.f, mvb = 0.f;
    if (have) {
        xva = x[gbase];      mva = mask[gbase];
        xvb = x[gbase + DD]; mvb = mask[gbase + DD];
    }

    // critical split (rows 0..207): waves 0-3 -> 28 rows, 4-7 -> 24 rows
    const int cr0  = (wv < 4) ? wv * 28 : 112 + (wv - 4) * 24;
    const int clen = (wv < 4) ? 28 : 24;

    unsigned gen = 0;

    for (int t = 0; t < SS; ++t) {
        const int sbase = t * SROWS;        // this step's slot (row units)

        // ---- Phase B: readout partials from h_t (virgin cached reads) ----
        {
            const float* hrow = buf + (size_t)(sbase + HOFF) * 64;
            const int jb = wv * 32;
            float acc0 = 0.f, acc1 = 0.f, acc2 = 0.f, acc3 = 0.f;
            #pragma unroll 4
            for (int j = 0; j < 32; j += 4) {
                float a0 = hrow[(jb + j + 0) * 64 + lane];
                float a1 = hrow[(jb + j + 1) * 64 + lane];
                float a2 = hrow[(jb + j + 2) * 64 + lane];
                float a3 = hrow[(jb + j + 3) * 64 + lane];
                float4 w0 = *(const float4*)&wrol[0 * ROW + jb + j];
                float4 w1 = *(const float4*)&wrol[1 * ROW + jb + j];
                float4 w2 = *(const float4*)&wrol[2 * ROW + jb + j];
                float4 w3 = *(const float4*)&wrol[3 * ROW + jb + j];
                acc0 += a0*w0.x + a1*w0.y + a2*w0.z + a3*w0.w;
                acc1 += a0*w1.x + a1*w1.y + a2*w1.z + a3*w1.w;
                acc2 += a0*w2.x + a1*w2.y + a2*w2.z + a3*w2.w;
                acc3 += a0*w3.x + a1*w3.y + a2*w3.z + a3*w3.w;
            }
            redB[(wv * 4 + 0) * 64 + lane] = acc0;
            redB[(wv * 4 + 1) * 64 + lane] = acc1;
            redB[(wv * 4 + 2) * 64 + lane] = acc2;
            redB[(wv * 4 + 3) * 64 + lane] = acc3;
        }
        __syncthreads();
        if (have) {
            float xh = brol[dl];
            #pragma unroll
            for (int g = 0; g < 8; ++g)
                xh += redB[(g * 4 + dl) * 64 + b];
            stage[(t * DD + d0 + dl) * 64 + b] = xh;   // coalesced, normal
            if (t < SS - 1) {
                float xi = (mva > 0.5f) ? xva : xh;
                ast4(&buf[(size_t)(sbase + d0 + dl) * 64 + b], xi);        // sc1
                if (t < 2)  // slots 0,1: mask in-band (pipeline not warm yet)
                    ast4(&buf[(size_t)(sbase + 207 + d0 + dl) * 64 + b], mva);
            }
        }
        if (t == SS - 1) break;

        // ---- arrive 1: xin_t published ----
        ++gen;
        asm volatile("s_waitcnt vmcnt(0)" ::: "memory");
        __syncthreads();
        if (tid == 0)
            __hip_atomic_store(&flags[wg * 32], gen, __ATOMIC_RELAXED, AG);

        // ---- overlap: gh partials from h_t (L1/L2-hot: same rows as Phase B) ----
        run_range6(A4, wgl, red, u, bp, 416 + wv * 32, sbase + HOFF + wv * 32, 32, 8 + wv);

        // ---- wait 1 ----
        if (tid < 64) {
            unsigned* f = &flags[tid * 32];
            while (__hip_atomic_load(f, __ATOMIC_RELAXED, AG) < gen) {}
        }
        __syncthreads();

        // ---- critical GEMV ----
        if (t < 2) {
            // v7 path: full 416 rows (mask in-band), 52 rows/wave
            run_range6(A4, wgl, red, u, bp, wv * 52, sbase + wv * 52, 52, wv);
        } else {
            // rows 0..207 only (x_p + mask col 0): 28/24 rows per wave
            run_range6(A4, wgl, red, u, bp, cr0, sbase + cr0, clen, wv);
        }
        __syncthreads();

        // ---- combine + gates + publish h_{t+1} into slot t+1 (sc1) ----
        if (tid < 256) {
            const int u2 = tid >> 6, b2 = tid & 63;
            float gir = bihl[0 + u2], giz = bihl[4 + u2], gin = bihl[8 + u2];
            float ghr = bhhl[0 + u2], ghz = bhhl[4 + u2], ghn = bhhl[8 + u2];
            #pragma unroll
            for (int s = 0; s < 8; ++s) {
                gir += red[(s * 12 + 0 + u2) * 64 + b2]
                     + red[((16 + s) * 12 + 0 + u2) * 64 + b2];
                giz += red[(s * 12 + 4 + u2) * 64 + b2]
                     + red[((16 + s) * 12 + 4 + u2) * 64 + b2];
                gin += red[(s * 12 + 8 + u2) * 64 + b2]
                     + red[((16 + s) * 12 + 8 + u2) * 64 + b2];
                ghr += red[((8 + s) * 12 + 0 + u2) * 64 + b2];
                ghz += red[((8 + s) * 12 + 4 + u2) * 64 + b2];
                ghn += red[((8 + s) * 12 + 8 + u2) * 64 + b2];
            }
            float r = 1.f / (1.f + __expf(-(gir + ghr)));
            float z = 1.f / (1.f + __expf(-(giz + ghz)));
            float n = tanhf(gin + r * ghn);
            float hn = (1.f - z) * n + z * hloc[u2 * 64 + b2];
            hloc[u2 * 64 + b2] = hn;
            ast4(&buf[(size_t)((t + 1) * SROWS + HOFF + wg * 4 + u2) * 64 + b2], hn);
        }

        // ---- arrive 2: h_{t+1} published ----
        ++gen;
        asm volatile("s_waitcnt vmcnt(0)" ::: "memory");
        __syncthreads();
        if (tid == 0)
            __hip_atomic_store(&flags[wg * 32], gen, __ATOMIC_RELAXED, AG);

        // ==== barrier-2 shadow ====
        // (a) load inputs for t+2; publish mask rows of slot t+2 (depth-2:
        //     drained by NEXT arr1's vmcnt; read only after matching wait1)
        float xvc = 0.f, mvc = 0.f;
        if (have && t + 2 <= SS - 2) {
            xvc = x[gbase + (size_t)(t + 2) * DD];
            mvc = mask[gbase + (size_t)(t + 2) * DD];
            ast4(&buf[(size_t)((t + 2) * SROWS + 207 + d0 + dl) * 64 + b], mvc);
        }
        // (b) mask-part GEMV for step t+1 (rows 208..415 of slot t+1; W cols
        //     208..413 real + 414/415 zero) -> red slots 16-23, consumed by
        //     iter t+1's combine (combine reads BEFORE next shadow overwrite)
        if (t >= 1 && t + 1 <= SS - 2) {
            run_range6(A4, wgl, red, u, bp, 208 + cr0,
                       (t + 1) * SROWS + 208 + cr0, clen, 16 + wv);
        }
        // rotate input pipeline
        xva = xvb; mva = mvb; xvb = xvc; mvb = mvc;

        // ---- wait 2 ----
        if (tid < 64) {
            unsigned* f = &flags[tid * 32];
            while (__hip_atomic_load(f, __ATOMIC_RELAXED, AG) < gen) {}
        }
        __syncthreads();
    }
}

// epilogue: stage[t][d][b] -> out[b][t][d]
__global__ __launch_bounds__(256) void out_transpose(
    const float* __restrict__ stage, float* __restrict__ out)
{
    __shared__ float lds[DD * 65];
    const int t = blockIdx.x;
    const float* st = stage + (size_t)t * DD * 64;
    for (int i = threadIdx.x; i < DD * 64; i += 256) {
        int d = i >> 6, b = i & 63;
        lds[d * 65 + b] = st[i];
    }
    __syncthreads();
    for (int i = threadIdx.x; i < DD * 64; i += 256) {
        int b = i / DD, d = i - b * DD;
        out[(size_t)b * (SS * DD) + (size_t)t * DD + d] = lds[d * 65 + b];
    }
}

// ================= v3 middle fallback (round-3 proven, 8.1 ms) =================
__device__ __forceinline__ void v3_gbar(unsigned* flags, int wg, unsigned g) {
    __syncthreads();
    if (threadIdx.x < 64) {
        if (threadIdx.x == 0) {
            __builtin_amdgcn_fence(__ATOMIC_RELEASE, "agent");
            __hip_atomic_store(&flags[wg * 32], g, __ATOMIC_RELAXED, AG);
        }
        unsigned* f = &flags[threadIdx.x * 32];
        while (__hip_atomic_load(f, __ATOMIC_RELAXED, AG) < g) { }
        __builtin_amdgcn_fence(__ATOMIC_ACQUIRE, "agent");
    }
    __syncthreads();
}

__global__ __launch_bounds__(256) void v3_init(float* __restrict__ ws) {
    int i = blockIdx.x * blockDim.x + threadIdx.x;
    const int nz = (672 - 414) * 64;
    for (int idx = i; idx < nz; idx += gridDim.x * blockDim.x)
        ws[414 * 64 + idx] = 0.f;
    for (int idx = i; idx < V3_FLAGS; idx += gridDim.x * blockDim.x)
        ((unsigned*)(ws + V3_ACT))[idx] = 0u;
}

template<bool STAGE>
__global__ __launch_bounds__(256) void v3_persist(
    const float* __restrict__ x, const float* __restrict__ mask,
    const float* __restrict__ W_ih, const float* __restrict__ W_hh,
    const float* __restrict__ b_ih, const float* __restrict__ b_hh,
    const float* __restrict__ W_ro, const float* __restrict__ b_ro,
    float* __restrict__ ws, float* __restrict__ out)
{
    const int wg = blockIdx.x;
    const int tid = threadIdx.x;
    const int lane = tid & 63;
    const int wv = tid >> 6;

    float* actg = ws;
    unsigned* flags = (unsigned*)(ws + V3_ACT);
    float* stage = ws + V3_ACT + V3_FLAGS;

    __shared__ float wgl[12 * LDW];
    __shared__ float wrol[4 * 256];
    __shared__ float red[5 * 12 * 64];
    __shared__ float redB[16 * 64];
    __shared__ float hloc[4 * 64];
    __shared__ float bihl[12], bhhl[12], brol[4];

    const int d0 = (207 * wg) / NWG;
    const int d1 = (207 * (wg + 1)) / NWG;
    const int dc = d1 - d0;

    for (int i = tid; i < 12 * LDW; i += 256) {
        int r = i / LDW, c = i - r * LDW;
        int rg = (r >> 2) * 256 + wg * 4 + (r & 3);
        float v = 0.f;
        if (c < 414) v = W_ih[rg * 414 + c];
        else if (c >= 416 && c < 672) v = W_hh[rg * 256 + (c - 416)];
        wgl[i] = v;
    }
    for (int i = tid; i < 4 * 256; i += 256) {
        int dl_ = i >> 8, j = i & 255;
        wrol[i] = (dl_ < dc) ? W_ro[(d0 + dl_) * 256 + j] : 0.f;
    }
    if (tid < 12) {
        int rg = (tid >> 2) * 256 + wg * 4 + (tid & 3);
        bihl[tid] = b_ih[rg];
        bhhl[tid] = b_hh[rg];
    }
    if (tid < 4) brol[tid] = (tid < dc) ? b_ro[d0 + tid] : 0.f;
    hloc[tid] = 0.f;
    __syncthreads();

    const float4* A4 = (const float4*)actg;
    const int u = lane >> 4;
    const int bp = lane & 15;

    const bool have = (tid < dc * 64);
    const int dl = tid >> 6, b = tid & 63;
    const size_t gbase = (size_t)b * (SS * DD) + (d0 + dl);
    float xv_pf = 0.f, mv_pf = 0.f;
    if (have) { xv_pf = x[gbase]; mv_pf = mask[gbase]; }

    unsigned gen = 0;

    for (int t = 0; t < SS; ++t) {
        const int par = t & 1;
        const int hrow0 = V3_HBASE + par * 256;

        {
            const float* hrow = actg + hrow0 * 64;
            const int jb = wv * 64;
            float acc0 = 0.f, acc1 = 0.f, acc2 = 0.f, acc3 = 0.f;
            #pragma unroll 4
            for (int j = 0; j < 64; j += 4) {
                float a0 = hrow[(jb + j + 0) * 64 + lane];
                float a1 = hrow[(jb + j + 1) * 64 + lane];
                float a2 = hrow[(jb + j + 2) * 64 + lane];
                float a3 = hrow[(jb + j + 3) * 64 + lane];
                float4 w0 = *(const float4*)&wrol[0 * 256 + jb + j];
                float4 w1 = *(const float4*)&wrol[1 * 256 + jb + j];
                float4 w2 = *(const float4*)&wrol[2 * 256 + jb + j];
                float4 w3 = *(const float4*)&wrol[3 * 256 + jb + j];
                acc0 += a0*w0.x + a1*w0.y + a2*w0.z + a3*w0.w;
                acc1 += a0*w1.x + a1*w1.y + a2*w1.z + a3*w1.w;
                acc2 += a0*w2.x + a1*w2.y + a2*w2.z + a3*w2.w;
                acc3 += a0*w3.x + a1*w3.y + a2*w3.z + a3*w3.w;
            }
            redB[(wv * 4 + 0) * 64 + lane] = acc0;
            redB[(wv * 4 + 1) * 64 + lane] = acc1;
            redB[(wv * 4 + 2) * 64 + lane] = acc2;
            redB[(wv * 4 + 3) * 64 + lane] = acc3;
        }
        __syncthreads();
        if (have) {
            float xh = redB[(0 * 4 + dl) * 64 + b] + redB[(1 * 4 + dl) * 64 + b]
                     + redB[(2 * 4 + dl) * 64 + b] + redB[(3 * 4 + dl) * 64 + b]
                     + brol[dl];
            if (STAGE) stage[(t * DD + d0 + dl) * 64 + b] = xh;
            else       out[gbase + (size_t)t * DD] = xh;
            if (t < SS - 1) {
                float xi = (mv_pf > 0.5f) ? xv_pf : xh;
                actg[(d0 + dl) * 64 + b] = xi;
                actg[(207 + d0 + dl) * 64 + b] = mv_pf;
            }
        }
        if (t == SS - 1) break;

        if (have && t + 1 < SS - 1) {
            xv_pf = x[gbase + (size_t)(t + 1) * DD];
            mv_pf = mask[gbase + (size_t)(t + 1) * DD];
        }

        v3_gbar(flags, wg, ++gen);

        if (wv == 0)      run_range6(A4, wgl, red, u, bp, 0,   0,          168, 0);
        else if (wv == 1) run_range6(A4, wgl, red, u, bp, 168, 168,        168, 1);
        else if (wv == 2) {
            run_range6(A4, wgl, red, u, bp, 336, 336,        80,  2);
            run_range6(A4, wgl, red, u, bp, 416, hrow0,      96,  3);
        } else            run_range6(A4, wgl, red, u, bp, 512, hrow0 + 96, 160, 4);
        __syncthreads();
        {
            const int u2 = tid >> 6, b2 = tid & 63;
            float gir = red[(0*12 + 0 + u2)*64 + b2] + red[(1*12 + 0 + u2)*64 + b2]
                      + red[(2*12 + 0 + u2)*64 + b2] + bihl[0 + u2];
            float giz = red[(0*12 + 4 + u2)*64 + b2] + red[(1*12 + 4 + u2)*64 + b2]
                      + red[(2*12 + 4 + u2)*64 + b2] + bihl[4 + u2];
            float gin = red[(0*12 + 8 + u2)*64 + b2] + red[(1*12 + 8 + u2)*64 + b2]
                      + red[(2*12 + 8 + u2)*64 + b2] + bihl[8 + u2];
            float ghr = red[(3*12 + 0 + u2)*64 + b2] + red[(4*12 + 0 + u2)*64 + b2] + bhhl[0 + u2];
            float ghz = red[(3*12 + 4 + u2)*64 + b2] + red[(4*12 + 4 + u2)*64 + b2] + bhhl[4 + u2];
            float ghn = red[(3*12 + 8 + u2)*64 + b2] + red[(4*12 + 8 + u2)*64 + b2] + bhhl[8 + u2];
            float r = 1.f / (1.f + __expf(-(gir + ghr)));
            float z = 1.f / (1.f + __expf(-(giz + ghz)));
            float n = tanhf(gin + r * ghn);
            float hn = (1.f - z) * n + z * hloc[u2 * 64 + b2];
            hloc[u2 * 64 + b2] = hn;
            actg[(V3_HBASE + (par ^ 1) * 256 + wg * 4 + u2) * 64 + b2] = hn;
        }
        v3_gbar(flags, wg, ++gen);
    }
}

// ---- minimal fallback (one WG per batch) ----
__global__ __launch_bounds__(768) void rnn_fallback(
    const float* __restrict__ x, const float* __restrict__ mask,
    const float* __restrict__ W_ih, const float* __restrict__ W_hh,
    const float* __restrict__ b_ih, const float* __restrict__ b_hh,
    const float* __restrict__ W_ro, const float* __restrict__ b_ro,
    float* __restrict__ out)
{
    const int b = blockIdx.x, tid = threadIdx.x;
    __shared__ float h[HH];
    __shared__ float hnew[HH];
    __shared__ float xin[414 + 2];
    __shared__ float gi[768];
    __shared__ float gh[768];
    __shared__ float xhat[DD];
    const float bih = b_ih[tid], bhh = b_hh[tid];
    const float bro = (tid < DD) ? b_ro[tid] : 0.f;
    if (tid < HH) h[tid] = 0.f;
    if (tid < DD) xhat[tid] = bro;
    __syncthreads();
    const float* xb = x + (size_t)b * SS * DD;
    const float* mb = mask + (size_t)b * SS * DD;
    float* ob = out + (size_t)b * SS * DD;
    for (int t = 0; t < SS; ++t) {
        if (tid < DD) ob[t * DD + tid] = xhat[tid];
        if (t == SS - 1) break;
        if (tid < DD) {
            float m = mb[t * DD + tid], xv = xb[t * DD + tid];
            xin[tid] = (m > 0.5f) ? xv : xhat[tid];
            xin[DD + tid] = m;
        }
        __syncthreads();
        float accI = bih, accH = bhh;
        const float* wi = W_ih + (size_t)tid * 414;
        for (int k = 0; k < 414; ++k) accI += wi[k] * xin[k];
        const float* wh = W_hh + (size_t)tid * HH;
        for (int k = 0; k < HH; ++k) accH += wh[k] * h[k];
        gi[tid] = accI; gh[tid] = accH;
        __syncthreads();
        if (tid < HH) {
            float r = 1.f / (1.f + __expf(-(gi[tid] + gh[tid])));
            float z = 1.f / (1.f + __expf(-(gi[HH + tid] + gh[HH + tid])));
            float n = tanhf(gi[2 * HH + tid] + r * gh[2 * HH + tid]);
            hnew[tid] = (1.f - z) * n + z * h[tid];
        }
        __syncthreads();
        if (tid < DD) {
            float acc = bro;
            const float* wr = W_ro + (size_t)tid * HH;
            for (int k = 0; k < HH; ++k) acc += wr[k] * hnew[k];
            xhat[tid] = acc;
        }
        if (tid < HH) h[tid] = hnew[tid];
        __syncthreads();
    }
}

extern "C" void kernel_launch(void* const* d_in, const int* in_sizes, int n_in,
                              void* d_out, int out_size, void* d_ws, size_t ws_size,
                              hipStream_t stream) {
    const float* x    = (const float*)d_in[0];
    const float* mask = (const float*)d_in[1];
    const float* W_ih = (const float*)d_in[2];
    const float* W_hh = (const float*)d_in[3];
    const float* b_ih = (const float*)d_in[4];
    const float* b_hh = (const float*)d_in[5];
    const float* W_ro = (const float*)d_in[6];
    const float* b_ro = (const float*)d_in[7];
    float* out = (float*)d_out;
    float* ws  = (float*)d_ws;

    if (ws_size >= WS_NEED6) {
        hipLaunchKernelGGL(rnn_init6, dim3(64), dim3(256), 0, stream, ws);
        hipLaunchKernelGGL(rnn_persist12, dim3(NWG), dim3(512), 0, stream,
                           x, mask, W_ih, W_hh, b_ih, b_hh, W_ro, b_ro, ws, out);
        hipLaunchKernelGGL(out_transpose, dim3(SS), dim3(256), 0, stream,
                           ws + BUF_FLOATS + FLAG_U32, out);
    } else if (ws_size >= V3_WS_FULL) {
        hipLaunchKernelGGL(v3_init, dim3(32), dim3(256), 0, stream, ws);
        hipLaunchKernelGGL((v3_persist<true>), dim3(NWG), dim3(256), 0, stream,
                           x, mask, W_ih, W_hh, b_ih, b_hh, W_ro, b_ro, ws, out);
        hipLaunchKernelGGL(out_transpose, dim3(SS), dim3(256), 0, stream,
                           ws + V3_ACT + V3_FLAGS, out);
    } else if (ws_size >= V3_WS_SMALL) {
        hipLaunchKernelGGL(v3_init, dim3(32), dim3(256), 0, stream, ws);
        hipLaunchKernelGGL((v3_persist<false>), dim3(NWG), dim3(256), 0, stream,
                           x, mask, W_ih, W_hh, b_ih, b_hh, W_ro, b_ro, ws, out);
    } else {
        hipLaunchKernelGGL(rnn_fallback, dim3(BB), dim3(768), 0, stream,
                           x, mask, W_ih, W_hh, b_ih, b_hh, W_ro, b_ro, out);
    }
}

// Round 7
// 4939.811 us; speedup vs baseline: 1.3999x; 1.2165x over previous
//
#include <hip/hip_runtime.h>
#include <math.h>

#define BB 64
#define SS 512
#define DD 207
#define HH 256
#define NWG 64
#define LDW 676   // wgl row stride (%32==4 -> staggered banks)
#define ROW 260   // wrol row stride
#define AG __HIP_MEMORY_SCOPE_AGENT

// ================= v13: v7 + gh fused into Phase B (pass deleted) ============
// 64 WGs x 512 threads (8 waves, 2/SIMD — proven v7 config). Protocol, layout,
// flags identical to v7 (step-slot rotation, sc1 publishes, virgin cached
// reads, monotone flags, 2 barriers/step). Change: Phase B and the gh GEMV
// read the SAME 256 h-rows — fuse them. Phase B now uses the float4 lane map
// (u = row-group, bp = batch-quad): each thread accumulates gate rows
// {u,4+u,8+u} (-> red slots 8..15) AND readout row u (-> redB) from one load
// stream. The post-arr1 gh pass is DELETED (arr1 shadow empty; v12 proved
// spins ~0 so nothing is lost). The stage (output) store is deferred past the
// arr1 flag, shrinking the drain set to the 2 xin publishes.
#define SROWS 672
#define HOFF  416
#define SLOT  (SROWS * 64)
#define BUF_FLOATS ((size_t)SS * SLOT)
#define FLAG_U32 (64 * 32)
#define STAGE_FLOATS ((size_t)SS * DD * 64)
#define WS_NEED6 ((BUF_FLOATS + FLAG_U32 + STAGE_FLOATS) * sizeof(float))

// ---- v3 fallback layout (round-3 proven path) ----
#define V3_AROWS 928
#define V3_HBASE 416
#define V3_ACT (V3_AROWS * 64)
#define V3_FLAGS (64 * 32)
#define V3_WS_SMALL ((size_t)(V3_ACT + V3_FLAGS) * sizeof(float))
#define V3_WS_FULL  ((size_t)(V3_ACT + V3_FLAGS + STAGE_FLOATS) * sizeof(float))

__device__ __forceinline__ void ast4(float* p, float v) {
    union { float f; unsigned u; } c; c.f = v;
    __hip_atomic_store((unsigned*)p, c.u, __ATOMIC_RELAXED, AG);
}

// 12-row (3 gates x unit u) GEMV partial, NORMAL float4 loads (round-3 shape).
// gr0 = global float4-row base (t*672 + local row), wc0 = weight col base.
__device__ __forceinline__ void run_range6(
    const float4* __restrict__ A4, const float* __restrict__ wgl,
    float* __restrict__ red, int u, int bp, int wc0, int gr0, int len, int slot)
{
    float4 c0 = make_float4(0.f, 0.f, 0.f, 0.f);
    float4 c1 = c0, c2 = c0;
    #pragma unroll 4
    for (int k = 0; k < len; k += 4) {
        float4 a0 = A4[(gr0 + k + 0) * 16 + bp];
        float4 a1 = A4[(gr0 + k + 1) * 16 + bp];
        float4 a2 = A4[(gr0 + k + 2) * 16 + bp];
        float4 a3 = A4[(gr0 + k + 3) * 16 + bp];
        float4 w0 = *(const float4*)&wgl[(0 + u) * LDW + wc0 + k];
        float4 w1 = *(const float4*)&wgl[(4 + u) * LDW + wc0 + k];
        float4 w2 = *(const float4*)&wgl[(8 + u) * LDW + wc0 + k];
        c0.x += a0.x*w0.x + a1.x*w0.y + a2.x*w0.z + a3.x*w0.w;
        c0.y += a0.y*w0.x + a1.y*w0.y + a2.y*w0.z + a3.y*w0.w;
        c0.z += a0.z*w0.x + a1.z*w0.y + a2.z*w0.z + a3.z*w0.w;
        c0.w += a0.w*w0.x + a1.w*w0.y + a2.w*w0.z + a3.w*w0.w;
        c1.x += a0.x*w1.x + a1.x*w1.y + a2.x*w1.z + a3.x*w1.w;
        c1.y += a0.y*w1.x + a1.y*w1.y + a2.y*w1.z + a3.y*w1.w;
        c1.z += a0.z*w1.x + a1.z*w1.y + a2.z*w1.z + a3.z*w1.w;
        c1.w += a0.w*w1.x + a1.w*w1.y + a2.w*w1.z + a3.w*w1.w;
        c2.x += a0.x*w2.x + a1.x*w2.y + a2.x*w2.z + a3.x*w2.w;
        c2.y += a0.y*w2.x + a1.y*w2.y + a2.y*w2.z + a3.y*w2.w;
        c2.z += a0.z*w2.x + a1.z*w2.y + a2.z*w2.z + a3.z*w2.w;
        c2.w += a0.w*w2.x + a1.w*w2.y + a2.w*w2.z + a3.w*w2.w;
    }
    float4* R4 = (float4*)red;
    R4[(slot * 12 + 0 + u) * 16 + bp] = c0;
    R4[(slot * 12 + 4 + u) * 16 + bp] = c1;
    R4[(slot * 12 + 8 + u) * 16 + bp] = c2;
}

__global__ __launch_bounds__(256) void rnn_init6(float* __restrict__ ws) {
    int i = blockIdx.x * blockDim.x + threadIdx.x;
    // zero slot-0 h rows (h_0 = 0)
    for (int idx = i; idx < HH * 64; idx += gridDim.x * blockDim.x)
        ws[HOFF * 64 + idx] = 0.f;
    unsigned* fl = (unsigned*)(ws + BUF_FLOATS);
    for (int idx = i; idx < FLAG_U32; idx += gridDim.x * blockDim.x)
        fl[idx] = 0u;
}

__global__ __launch_bounds__(512) void rnn_persist13(
    const float* __restrict__ x, const float* __restrict__ mask,
    const float* __restrict__ W_ih, const float* __restrict__ W_hh,
    const float* __restrict__ b_ih, const float* __restrict__ b_hh,
    const float* __restrict__ W_ro, const float* __restrict__ b_ro,
    float* __restrict__ ws, float* __restrict__ out)
{
    const int wg = blockIdx.x;
    const int tid = threadIdx.x;
    const int lane = tid & 63;
    const int wv = tid >> 6;          // 0..7

    float* buf = ws;
    unsigned* flags = (unsigned*)(ws + BUF_FLOATS);
    float* stage = ws + BUF_FLOATS + FLAG_U32;

    __shared__ float wgl[12 * LDW];      // 12 gate rows x 676 (cols 414/415 = 0)
    __shared__ float wrol[4 * ROW];      // up to 4 readout rows
    __shared__ float red[16 * 12 * 64];  // slots 0-7 xin partials, 8-15 gh
    __shared__ float redB[32 * 64];      // readout partials (8 waves x 4 rows)
    __shared__ float hloc[4 * 64];       // own hidden units
    __shared__ float bihl[12], bhhl[12], brol[4];

    const int d0 = (207 * wg) / NWG;
    const int d1 = (207 * (wg + 1)) / NWG;
    const int dc = d1 - d0;

    for (int i = tid; i < 12 * LDW; i += 512) {
        int r = i / LDW, c = i - r * LDW;
        int rg = (r >> 2) * 256 + wg * 4 + (r & 3);
        float v = 0.f;
        if (c < 414) v = W_ih[rg * 414 + c];
        else if (c >= 416 && c < 672) v = W_hh[rg * 256 + (c - 416)];
        wgl[i] = v;
    }
    for (int i = tid; i < 4 * 256; i += 512) {
        int dl_ = i >> 8, j = i & 255;
        wrol[dl_ * ROW + j] = (dl_ < dc) ? W_ro[(d0 + dl_) * 256 + j] : 0.f;
    }
    if (tid < 12) {
        int rg = (tid >> 2) * 256 + wg * 4 + (tid & 3);
        bihl[tid] = b_ih[rg];
        bhhl[tid] = b_hh[rg];
    }
    if (tid < 4) brol[tid] = (tid < dc) ? b_ro[d0 + tid] : 0.f;
    if (tid < 256) hloc[tid] = 0.f;
    __syncthreads();

    const float4* A4 = (const float4*)buf;
    const int u  = lane >> 4;
    const int bp = lane & 15;

    const bool have = (tid < dc * 64);
    const int dl = tid >> 6, b = tid & 63;
    const size_t gbase = (size_t)b * (SS * DD) + (d0 + dl);
    float xv_pf = 0.f, mv_pf = 0.f;
    if (have) { xv_pf = x[gbase]; mv_pf = mask[gbase]; }

    unsigned gen = 0;

    for (int t = 0; t < SS; ++t) {
        const int sbase = t * SROWS;        // this step's slot (row units)

        // ---- Fused Phase B + gh: ONE pass over h_t (float4, virgin reads) ----
        // Thread (wv,u,bp): cols jb..jb+32, gate rows {u,4+u,8+u} -> red slot
        // 8+wv, readout row u -> redB. Same loads serve both.
        {
            const int jb = wv * 32;
            const int gr0 = sbase + HOFF + jb;     // h rows (float4 rows)
            const int wc0 = 416 + jb;              // gate weight cols
            float4 c0 = make_float4(0.f, 0.f, 0.f, 0.f);
            float4 c1 = c0, c2 = c0, cR = c0;
            #pragma unroll 4
            for (int k = 0; k < 32; k += 4) {
                float4 a0 = A4[(gr0 + k + 0) * 16 + bp];
                float4 a1 = A4[(gr0 + k + 1) * 16 + bp];
                float4 a2 = A4[(gr0 + k + 2) * 16 + bp];
                float4 a3 = A4[(gr0 + k + 3) * 16 + bp];
                float4 w0 = *(const float4*)&wgl[(0 + u) * LDW + wc0 + k];
                float4 w1 = *(const float4*)&wgl[(4 + u) * LDW + wc0 + k];
                float4 w2 = *(const float4*)&wgl[(8 + u) * LDW + wc0 + k];
                float4 wR = *(const float4*)&wrol[u * ROW + jb + k];
                c0.x += a0.x*w0.x + a1.x*w0.y + a2.x*w0.z + a3.x*w0.w;
                c0.y += a0.y*w0.x + a1.y*w0.y + a2.y*w0.z + a3.y*w0.w;
                c0.z += a0.z*w0.x + a1.z*w0.y + a2.z*w0.z + a3.z*w0.w;
                c0.w += a0.w*w0.x + a1.w*w0.y + a2.w*w0.z + a3.w*w0.w;
                c1.x += a0.x*w1.x + a1.x*w1.y + a2.x*w1.z + a3.x*w1.w;
                c1.y += a0.y*w1.x + a1.y*w1.y + a2.y*w1.z + a3.y*w1.w;
                c1.z += a0.z*w1.x + a1.z*w1.y + a2.z*w1.z + a3.z*w1.w;
                c1.w += a0.w*w1.x + a1.w*w1.y + a2.w*w1.z + a3.w*w1.w;
                c2.x += a0.x*w2.x + a1.x*w2.y + a2.x*w2.z + a3.x*w2.w;
                c2.y += a0.y*w2.x + a1.y*w2.y + a2.y*w2.z + a3.y*w2.w;
                c2.z += a0.z*w2.x + a1.z*w2.y + a2.z*w2.z + a3.z*w2.w;
                c2.w += a0.w*w2.x + a1.w*w2.y + a2.w*w2.z + a3.w*w2.w;
                cR.x += a0.x*wR.x + a1.x*wR.y + a2.x*wR.z + a3.x*wR.w;
                cR.y += a0.y*wR.x + a1.y*wR.y + a2.y*wR.z + a3.y*wR.w;
                cR.z += a0.z*wR.x + a1.z*wR.y + a2.z*wR.z + a3.z*wR.w;
                cR.w += a0.w*wR.x + a1.w*wR.y + a2.w*wR.z + a3.w*wR.w;
            }
            float4* R4 = (float4*)red;
            R4[((8 + wv) * 12 + 0 + u) * 16 + bp] = c0;
            R4[((8 + wv) * 12 + 4 + u) * 16 + bp] = c1;
            R4[((8 + wv) * 12 + 8 + u) * 16 + bp] = c2;
            float4* RB4 = (float4*)redB;
            RB4[(wv * 4 + u) * 16 + bp] = cR;
        }
        __syncthreads();

        float xh = 0.f;
        if (have) {
            xh = brol[dl];
            #pragma unroll
            for (int g = 0; g < 8; ++g)
                xh += redB[(g * 4 + dl) * 64 + b];
            if (t < SS - 1) {
                float xi = (mv_pf > 0.5f) ? xv_pf : xh;
                ast4(&buf[(size_t)(sbase + d0 + dl) * 64 + b], xi);        // sc1
                ast4(&buf[(size_t)(sbase + 207 + d0 + dl) * 64 + b], mv_pf);
            }
        }
        if (t == SS - 1) {
            if (have) stage[(t * DD + d0 + dl) * 64 + b] = xh;
            break;
        }

        // ---- arrive 1: xin_t published (drain = 2 ast4 only) ----
        ++gen;
        asm volatile("s_waitcnt vmcnt(0)" ::: "memory");
        __syncthreads();
        if (tid == 0)
            __hip_atomic_store(&flags[wg * 32], gen, __ATOMIC_RELAXED, AG);

        // deferred output store (out of the drain set)
        if (have) stage[(t * DD + d0 + dl) * 64 + b] = xh;

        // ---- wait 1 ----
        if (tid < 64) {
            unsigned* f = &flags[tid * 32];
            while (__hip_atomic_load(f, __ATOMIC_RELAXED, AG) < gen) {}
        }
        __syncthreads();

        // ---- gate xin GEMV: 8 waves x 52 rows (virgin cached reads) ----
        run_range6(A4, wgl, red, u, bp, wv * 52, sbase + wv * 52, 52, wv);
        __syncthreads();

        // ---- combine + gates + publish h_{t+1} into slot t+1 (sc1) ----
        if (tid < 256) {
            const int u2 = tid >> 6, b2 = tid & 63;
            float gir = bihl[0 + u2], giz = bihl[4 + u2], gin = bihl[8 + u2];
            float ghr = bhhl[0 + u2], ghz = bhhl[4 + u2], ghn = bhhl[8 + u2];
            #pragma unroll
            for (int s = 0; s < 8; ++s) {
                gir += red[(s * 12 + 0 + u2) * 64 + b2];
                giz += red[(s * 12 + 4 + u2) * 64 + b2];
                gin += red[(s * 12 + 8 + u2) * 64 + b2];
                ghr += red[((8 + s) * 12 + 0 + u2) * 64 + b2];
                ghz += red[((8 + s) * 12 + 4 + u2) * 64 + b2];
                ghn += red[((8 + s) * 12 + 8 + u2) * 64 + b2];
            }
            float r = 1.f / (1.f + __expf(-(gir + ghr)));
            float z = 1.f / (1.f + __expf(-(giz + ghz)));
            float n = tanhf(gin + r * ghn);
            float hn = (1.f - z) * n + z * hloc[u2 * 64 + b2];
            hloc[u2 * 64 + b2] = hn;
            ast4(&buf[(size_t)((t + 1) * SROWS + HOFF + wg * 4 + u2) * 64 + b2], hn);
        }

        // ---- arrive 2: h_{t+1} published ----
        ++gen;
        asm volatile("s_waitcnt vmcnt(0)" ::: "memory");
        __syncthreads();
        if (tid == 0)
            __hip_atomic_store(&flags[wg * 32], gen, __ATOMIC_RELAXED, AG);

        // ---- overlap: next x/mask prefetch ----
        if (have && t + 1 < SS - 1) {
            xv_pf = x[gbase + (size_t)(t + 1) * DD];
            mv_pf = mask[gbase + (size_t)(t + 1) * DD];
        }

        // ---- wait 2 ----
        if (tid < 64) {
            unsigned* f = &flags[tid * 32];
            while (__hip_atomic_load(f, __ATOMIC_RELAXED, AG) < gen) {}
        }
        __syncthreads();
    }
}

// epilogue: stage[t][d][b] -> out[b][t][d]
__global__ __launch_bounds__(256) void out_transpose(
    const float* __restrict__ stage, float* __restrict__ out)
{
    __shared__ float lds[DD * 65];
    const int t = blockIdx.x;
    const float* st = stage + (size_t)t * DD * 64;
    for (int i = threadIdx.x; i < DD * 64; i += 256) {
        int d = i >> 6, b = i & 63;
        lds[d * 65 + b] = st[i];
    }
    __syncthreads();
    for (int i = threadIdx.x; i < DD * 64; i += 256) {
        int b = i / DD, d = i - b * DD;
        out[(size_t)b * (SS * DD) + (size_t)t * DD + d] = lds[d * 65 + b];
    }
}

// ================= v3 middle fallback (round-3 proven, 8.1 ms) =================
__device__ __forceinline__ void v3_gbar(unsigned* flags, int wg, unsigned g) {
    __syncthreads();
    if (threadIdx.x < 64) {
        if (threadIdx.x == 0) {
            __builtin_amdgcn_fence(__ATOMIC_RELEASE, "agent");
            __hip_atomic_store(&flags[wg * 32], g, __ATOMIC_RELAXED, AG);
        }
        unsigned* f = &flags[threadIdx.x * 32];
        while (__hip_atomic_load(f, __ATOMIC_RELAXED, AG) < g) { }
        __builtin_amdgcn_fence(__ATOMIC_ACQUIRE, "agent");
    }
    __syncthreads();
}

__global__ __launch_bounds__(256) void v3_init(float* __restrict__ ws) {
    int i = blockIdx.x * blockDim.x + threadIdx.x;
    const int nz = (672 - 414) * 64;
    for (int idx = i; idx < nz; idx += gridDim.x * blockDim.x)
        ws[414 * 64 + idx] = 0.f;
    for (int idx = i; idx < V3_FLAGS; idx += gridDim.x * blockDim.x)
        ((unsigned*)(ws + V3_ACT))[idx] = 0u;
}

template<bool STAGE>
__global__ __launch_bounds__(256) void v3_persist(
    const float* __restrict__ x, const float* __restrict__ mask,
    const float* __restrict__ W_ih, const float* __restrict__ W_hh,
    const float* __restrict__ b_ih, const float* __restrict__ b_hh,
    const float* __restrict__ W_ro, const float* __restrict__ b_ro,
    float* __restrict__ ws, float* __restrict__ out)
{
    const int wg = blockIdx.x;
    const int tid = threadIdx.x;
    const int lane = tid & 63;
    const int wv = tid >> 6;

    float* actg = ws;
    unsigned* flags = (unsigned*)(ws + V3_ACT);
    float* stage = ws + V3_ACT + V3_FLAGS;

    __shared__ float wgl[12 * LDW];
    __shared__ float wrol[4 * 256];
    __shared__ float red[5 * 12 * 64];
    __shared__ float redB[16 * 64];
    __shared__ float hloc[4 * 64];
    __shared__ float bihl[12], bhhl[12], brol[4];

    const int d0 = (207 * wg) / NWG;
    const int d1 = (207 * (wg + 1)) / NWG;
    const int dc = d1 - d0;

    for (int i = tid; i < 12 * LDW; i += 256) {
        int r = i / LDW, c = i - r * LDW;
        int rg = (r >> 2) * 256 + wg * 4 + (r & 3);
        float v = 0.f;
        if (c < 414) v = W_ih[rg * 414 + c];
        else if (c >= 416 && c < 672) v = W_hh[rg * 256 + (c - 416)];
        wgl[i] = v;
    }
    for (int i = tid; i < 4 * 256; i += 256) {
        int dl_ = i >> 8, j = i & 255;
        wrol[i] = (dl_ < dc) ? W_ro[(d0 + dl_) * 256 + j] : 0.f;
    }
    if (tid < 12) {
        int rg = (tid >> 2) * 256 + wg * 4 + (tid & 3);
        bihl[tid] = b_ih[rg];
        bhhl[tid] = b_hh[rg];
    }
    if (tid < 4) brol[tid] = (tid < dc) ? b_ro[d0 + tid] : 0.f;
    hloc[tid] = 0.f;
    __syncthreads();

    const float4* A4 = (const float4*)actg;
    const int u = lane >> 4;
    const int bp = lane & 15;

    const bool have = (tid < dc * 64);
    const int dl = tid >> 6, b = tid & 63;
    const size_t gbase = (size_t)b * (SS * DD) + (d0 + dl);
    float xv_pf = 0.f, mv_pf = 0.f;
    if (have) { xv_pf = x[gbase]; mv_pf = mask[gbase]; }

    unsigned gen = 0;

    for (int t = 0; t < SS; ++t) {
        const int par = t & 1;
        const int hrow0 = V3_HBASE + par * 256;

        {
            const float* hrow = actg + hrow0 * 64;
            const int jb = wv * 64;
            float acc0 = 0.f, acc1 = 0.f, acc2 = 0.f, acc3 = 0.f;
            #pragma unroll 4
            for (int j = 0; j < 64; j += 4) {
                float a0 = hrow[(jb + j + 0) * 64 + lane];
                float a1 = hrow[(jb + j + 1) * 64 + lane];
                float a2 = hrow[(jb + j + 2) * 64 + lane];
                float a3 = hrow[(jb + j + 3) * 64 + lane];
                float4 w0 = *(const float4*)&wrol[0 * 256 + jb + j];
                float4 w1 = *(const float4*)&wrol[1 * 256 + jb + j];
                float4 w2 = *(const float4*)&wrol[2 * 256 + jb + j];
                float4 w3 = *(const float4*)&wrol[3 * 256 + jb + j];
                acc0 += a0*w0.x + a1*w0.y + a2*w0.z + a3*w0.w;
                acc1 += a0*w1.x + a1*w1.y + a2*w1.z + a3*w1.w;
                acc2 += a0*w2.x + a1*w2.y + a2*w2.z + a3*w2.w;
                acc3 += a0*w3.x + a1*w3.y + a2*w3.z + a3*w3.w;
            }
            redB[(wv * 4 + 0) * 64 + lane] = acc0;
            redB[(wv * 4 + 1) * 64 + lane] = acc1;
            redB[(wv * 4 + 2) * 64 + lane] = acc2;
            redB[(wv * 4 + 3) * 64 + lane] = acc3;
        }
        __syncthreads();
        if (have) {
            float xh = redB[(0 * 4 + dl) * 64 + b] + redB[(1 * 4 + dl) * 64 + b]
                     + redB[(2 * 4 + dl) * 64 + b] + redB[(3 * 4 + dl) * 64 + b]
                     + brol[dl];
            if (STAGE) stage[(t * DD + d0 + dl) * 64 + b] = xh;
            else       out[gbase + (size_t)t * DD] = xh;
            if (t < SS - 1) {
                float xi = (mv_pf > 0.5f) ? xv_pf : xh;
                actg[(d0 + dl) * 64 + b] = xi;
                actg[(207 + d0 + dl) * 64 + b] = mv_pf;
            }
        }
        if (t == SS - 1) break;

        if (have && t + 1 < SS - 1) {
            xv_pf = x[gbase + (size_t)(t + 1) * DD];
            mv_pf = mask[gbase + (size_t)(t + 1) * DD];
        }

        v3_gbar(flags, wg, ++gen);

        if (wv == 0)      run_range6(A4, wgl, red, u, bp, 0,   0,          168, 0);
        else if (wv == 1) run_range6(A4, wgl, red, u, bp, 168, 168,        168, 1);
        else if (wv == 2) {
            run_range6(A4, wgl, red, u, bp, 336, 336,        80,  2);
            run_range6(A4, wgl, red, u, bp, 416, hrow0,      96,  3);
        } else            run_range6(A4, wgl, red, u, bp, 512, hrow0 + 96, 160, 4);
        __syncthreads();
        {
            const int u2 = tid >> 6, b2 = tid & 63;
            float gir = red[(0*12 + 0 + u2)*64 + b2] + red[(1*12 + 0 + u2)*64 + b2]
                      + red[(2*12 + 0 + u2)*64 + b2] + bihl[0 + u2];
            float giz = red[(0*12 + 4 + u2)*64 + b2] + red[(1*12 + 4 + u2)*64 + b2]
                      + red[(2*12 + 4 + u2)*64 + b2] + bihl[4 + u2];
            float gin = red[(0*12 + 8 + u2)*64 + b2] + red[(1*12 + 8 + u2)*64 + b2]
                      + red[(2*12 + 8 + u2)*64 + b2] + bihl[8 + u2];
            float ghr = red[(3*12 + 0 + u2)*64 + b2] + red[(4*12 + 0 + u2)*64 + b2] + bhhl[0 + u2];
            float ghz = red[(3*12 + 4 + u2)*64 + b2] + red[(4*12 + 4 + u2)*64 + b2] + bhhl[4 + u2];
            float ghn = red[(3*12 + 8 + u2)*64 + b2] + red[(4*12 + 8 + u2)*64 + b2] + bhhl[8 + u2];
            float r = 1.f / (1.f + __expf(-(gir + ghr)));
            float z = 1.f / (1.f + __expf(-(giz + ghz)));
            float n = tanhf(gin + r * ghn);
            float hn = (1.f - z) * n + z * hloc[u2 * 64 + b2];
            hloc[u2 * 64 + b2] = hn;
            actg[(V3_HBASE + (par ^ 1) * 256 + wg * 4 + u2) * 64 + b2] = hn;
        }
        v3_gbar(flags, wg, ++gen);
    }
}

// ---- minimal fallback (one WG per batch) ----
__global__ __launch_bounds__(768) void rnn_fallback(
    const float* __restrict__ x, const float* __restrict__ mask,
    const float* __restrict__ W_ih, const float* __restrict__ W_hh,
    const float* __restrict__ b_ih, const float* __restrict__ b_hh,
    const float* __restrict__ W_ro, const float* __restrict__ b_ro,
    float* __restrict__ out)
{
    const int b = blockIdx.x, tid = threadIdx.x;
    __shared__ float h[HH];
    __shared__ float hnew[HH];
    __shared__ float xin[414 + 2];
    __shared__ float gi[768];
    __shared__ float gh[768];
    __shared__ float xhat[DD];
    const float bih = b_ih[tid], bhh = b_hh[tid];
    const float bro = (tid < DD) ? b_ro[tid] : 0.f;
    if (tid < HH) h[tid] = 0.f;
    if (tid < DD) xhat[tid] = bro;
    __syncthreads();
    const float* xb = x + (size_t)b * SS * DD;
    const float* mb = mask + (size_t)b * SS * DD;
    float* ob = out + (size_t)b * SS * DD;
    for (int t = 0; t < SS; ++t) {
        if (tid < DD) ob[t * DD + tid] = xhat[tid];
        if (t == SS - 1) break;
        if (tid < DD) {
            float m = mb[t * DD + tid], xv = xb[t * DD + tid];
            xin[tid] = (m > 0.5f) ? xv : xhat[tid];
            xin[DD + tid] = m;
        }
        __syncthreads();
        float accI = bih, accH = bhh;
        const float* wi = W_ih + (size_t)tid * 414;
        for (int k = 0; k < 414; ++k) accI += wi[k] * xin[k];
        const float* wh = W_hh + (size_t)tid * HH;
        for (int k = 0; k < HH; ++k) accH += wh[k] * h[k];
        gi[tid] = accI; gh[tid] = accH;
        __syncthreads();
        if (tid < HH) {
            float r = 1.f / (1.f + __expf(-(gi[tid] + gh[tid])));
            float z = 1.f / (1.f + __expf(-(gi[HH + tid] + gh[HH + tid])));
            float n = tanhf(gi[2 * HH + tid] + r * gh[2 * HH + tid]);
            hnew[tid] = (1.f - z) * n + z * h[tid];
        }
        __syncthreads();
        if (tid < DD) {
            float acc = bro;
            const float* wr = W_ro + (size_t)tid * HH;
            for (int k = 0; k < HH; ++k) acc += wr[k] * hnew[k];
            xhat[tid] = acc;
        }
        if (tid < HH) h[tid] = hnew[tid];
        __syncthreads();
    }
}

extern "C" void kernel_launch(void* const* d_in, const int* in_sizes, int n_in,
                              void* d_out, int out_size, void* d_ws, size_t ws_size,
                              hipStream_t stream) {
    const float* x    = (const float*)d_in[0];
    const float* mask = (const float*)d_in[1];
    const float* W_ih = (const float*)d_in[2];
    const float* W_hh = (const float*)d_in[3];
    const float* b_ih = (const float*)d_in[4];
    const float* b_hh = (const float*)d_in[5];
    const float* W_ro = (const float*)d_in[6];
    const float* b_ro = (const float*)d_in[7];
    float* out = (float*)d_out;
    float* ws  = (float*)d_ws;

    if (ws_size >= WS_NEED6) {
        hipLaunchKernelGGL(rnn_init6, dim3(64), dim3(256), 0, stream, ws);
        hipLaunchKernelGGL(rnn_persist13, dim3(NWG), dim3(512), 0, stream,
                           x, mask, W_ih, W_hh, b_ih, b_hh, W_ro, b_ro, ws, out);
        hipLaunchKernelGGL(out_transpose, dim3(SS), dim3(256), 0, stream,
                           ws + BUF_FLOATS + FLAG_U32, out);
    } else if (ws_size >= V3_WS_FULL) {
        hipLaunchKernelGGL(v3_init, dim3(32), dim3(256), 0, stream, ws);
        hipLaunchKernelGGL((v3_persist<true>), dim3(NWG), dim3(256), 0, stream,
                           x, mask, W_ih, W_hh, b_ih, b_hh, W_ro, b_ro, ws, out);
        hipLaunchKernelGGL(out_transpose, dim3(SS), dim3(256), 0, stream,
                           ws + V3_ACT + V3_FLAGS, out);
    } else if (ws_size >= V3_WS_SMALL) {
        hipLaunchKernelGGL(v3_init, dim3(32), dim3(256), 0, stream, ws);
        hipLaunchKernelGGL((v3_persist<false>), dim3(NWG), dim3(256), 0, stream,
                           x, mask, W_ih, W_hh, b_ih, b_hh, W_ro, b_ro, ws, out);
    } else {
        hipLaunchKernelGGL(rnn_fallback, dim3(BB), dim3(768), 0, stream,
                           x, mask, W_ih, W_hh, b_ih, b_hh, W_ro, b_ro, out);
    }
}